// Round 7
// baseline (1531.317 us; speedup 1.0000x reference)
//
#include <hip/hip_runtime.h>

#define NB 8
#define NP 16384
#define NC 256
#define NH 128
#define NM 4096
#define NS 1024

typedef float v2f __attribute__((ext_vector_type(2)));

// ---------- helpers ----------
__device__ __forceinline__ unsigned long long make_key(float v, int n) {
  unsigned u = __float_as_uint(v);
  u = (u & 0x80000000u) ? ~u : (u | 0x80000000u);  // map float -> ascending uint
  unsigned d = ~u;                                 // descending
  return (((unsigned long long)d) << 32) | (unsigned)n;
}

// VALU-only 64-lane max (values >= 0), result broadcast via readlane(63).
__device__ __forceinline__ float wave_max_dpp(float v) {
#define DPPMAX(ctrl)                                                            \
  v = fmaxf(v, __int_as_float(__builtin_amdgcn_update_dpp(                      \
                 __float_as_int(v), __float_as_int(v), (ctrl), 0xf, 0xf, false)))
  DPPMAX(0xB1);   // quad_perm [1,0,3,2]  : xor 1
  DPPMAX(0x4E);   // quad_perm [2,3,0,1]  : xor 2
  DPPMAX(0x141);  // row_half_mirror
  DPPMAX(0x140);  // row_mirror
  DPPMAX(0x142);  // row_bcast15
  DPPMAX(0x143);  // row_bcast31
#undef DPPMAX
  return __int_as_float(__builtin_amdgcn_readlane(__float_as_int(v), 63));
}

// 64-bit DPP lane-shuffle (both halves), compile-time ctrl
template <int CTRL>
__device__ __forceinline__ unsigned long long dpp64(unsigned long long v) {
  int lo = (int)(unsigned)v, hi = (int)(unsigned)(v >> 32);
  lo = __builtin_amdgcn_update_dpp(lo, lo, CTRL, 0xf, 0xf, false);
  hi = __builtin_amdgcn_update_dpp(hi, hi, CTRL, 0xf, 0xf, false);
  return (((unsigned long long)(unsigned)hi) << 32) | (unsigned)lo;
}

// ---------- transpose [H,C] -> [C,H] for both MLP weights ----------
__global__ __launch_bounds__(256) void transpose_w_kernel(
    const float* __restrict__ wseg, const float* __restrict__ wvote,
    float* __restrict__ tseg, float* __restrict__ tvote) {
  int i = blockIdx.x * 256 + threadIdx.x;  // 0..32767
  int c = i >> 7, o = i & 127;
  tseg[i] = wseg[o * NC + c];
  tvote[i] = wvote[o * NC + c];
}

// ---------- seg branch ----------
__global__ __launch_bounds__(256) void seg_kernel(
    const float* __restrict__ features, const float* __restrict__ w1t,
    const float* __restrict__ scale1, const float* __restrict__ bias1,
    const float* __restrict__ w2, const float* __restrict__ b2,
    float* __restrict__ seg_out, unsigned long long* __restrict__ keys) {
  __shared__ float wt[32][128];
  __shared__ float ft[32][64];
  __shared__ float red[16][64];
  __shared__ float Ssh[64];
  __shared__ float w2sh[128];
  int b = blockIdx.y;
  int n0 = blockIdx.x * 64;
  int tid = threadIdx.x;
  int lane = tid & 63;
  int ro = tid >> 4, rc = tid & 15;
  float a0 = w2[lane], a1 = w2[lane + 64];
  float whi = fmaxf(a0, a1), wlo = fminf(a0, a1);
#pragma unroll
  for (int off = 32; off >= 1; off >>= 1) {
    whi = fmaxf(whi, __shfl_xor(whi, off, 64));
    wlo = fminf(wlo, __shfl_xor(wlo, off, 64));
  }
  if (tid < 128) w2sh[tid] = w2[tid];
  const float* fb = features + (size_t)b * NC * NP;
  float acc[8][4] = {};
  for (int kc = 0; kc < NC; kc += 32) {
    for (int q = tid; q < 4096; q += 256) {
      int kk = q >> 7, o = q & 127;
      wt[kk][o] = w1t[(kc + kk) * NH + o];
    }
    for (int q = tid; q < 2048; q += 256) {
      int kk = q >> 6, nn = q & 63;
      ft[kk][nn] = fb[(size_t)(kc + kk) * NP + n0 + nn];
    }
    __syncthreads();
#pragma unroll
    for (int kk = 0; kk < 32; ++kk) {
      float wv[8], fv[4];
#pragma unroll
      for (int i = 0; i < 8; ++i) wv[i] = wt[kk][ro * 8 + i];
#pragma unroll
      for (int j = 0; j < 4; ++j) fv[j] = ft[kk][rc * 4 + j];
#pragma unroll
      for (int i = 0; i < 8; ++i)
#pragma unroll
        for (int j = 0; j < 4; ++j) acc[i][j] = fmaf(wv[i], fv[j], acc[i][j]);
    }
    __syncthreads();
  }
  float part[4] = {};
#pragma unroll
  for (int i = 0; i < 8; ++i) {
    int o = ro * 8 + i;
    float sc = scale1[o], bi = bias1[o];
#pragma unroll
    for (int j = 0; j < 4; ++j) {
      float h = fmaxf(fmaf(acc[i][j], sc, bi), 0.0f);
      part[j] += h;
    }
  }
#pragma unroll
  for (int j = 0; j < 4; ++j) red[ro][rc * 4 + j] = part[j];
  __syncthreads();
  float b2v = b2[0];
  if (tid < 64) {
    float S = 0.0f;
#pragma unroll
    for (int r = 0; r < 16; ++r) S += red[r][tid];
    Ssh[tid] = S;
    float m = (S >= 0.0f ? whi * S : wlo * S) + b2v;
    float sig = 1.0f / (1.0f + expf(-m));
    int nn = n0 + tid;
    keys[(size_t)b * NP + nn] = make_key(sig, nn);
  }
  __syncthreads();
  int n = tid & 63, kg = tid >> 6;
  float S = Ssh[n];
  size_t base = ((size_t)b * 128 + (size_t)kg * 32) * NP + n0 + n;
#pragma unroll
  for (int kk = 0; kk < 32; ++kk)
    seg_out[base + (size_t)kk * NP] = fmaf(w2sh[kg * 32 + kk], S, b2v);
}

// ---------- bitonic sort of each 8192-key chunk (chunk0 asc, chunk1 desc) ----------
__global__ __launch_bounds__(1024) void sort8k_kernel(unsigned long long* __restrict__ keys) {
  __shared__ unsigned long long sk[8192];
  int chunk = blockIdx.x & 1, b = blockIdx.x >> 1;
  bool desc = (chunk == 1);
  unsigned long long* K = keys + (size_t)b * NP + chunk * 8192;
  int tid = threadIdx.x;
  for (int i = tid; i < 8192; i += 1024) sk[i] = K[i];
  __syncthreads();
  for (int k = 2; k <= 8192; k <<= 1) {
    for (int j = k >> 1; j > 0; j >>= 1) {
      for (int i = tid; i < 8192; i += 1024) {
        int ixj = i ^ j;
        if (ixj > i) {
          bool up = (((i & k) == 0) != desc);
          unsigned long long a = sk[i], c = sk[ixj];
          if ((a > c) == up) { sk[i] = c; sk[ixj] = a; }
        }
      }
      __syncthreads();
    }
  }
  for (int i = tid; i < 8192; i += 1024) K[i] = sk[i];
}

// ---------- bitonic merge of lower half: exact top-4096 in sorted order ----------
__global__ __launch_bounds__(1024) void merge_topk_kernel(
    const unsigned long long* __restrict__ keys, int* __restrict__ fg_idx,
    float* __restrict__ fg_xyz, const float* __restrict__ xyz) {
  __shared__ unsigned long long sk[8192];
  int b = blockIdx.x;
  const unsigned long long* K = keys + (size_t)b * NP;
  int tid = threadIdx.x;
  for (int i = tid; i < 8192; i += 1024) {
    unsigned long long a = K[i], c = K[i + 8192];
    sk[i] = (a < c) ? a : c;
  }
  __syncthreads();
  for (int j = 4096; j > 0; j >>= 1) {
    for (int i = tid; i < 8192; i += 1024) {
      int ixj = i ^ j;
      if (ixj > i) {
        unsigned long long a = sk[i], c = sk[ixj];
        if (a > c) { sk[i] = c; sk[ixj] = a; }
      }
    }
    __syncthreads();
  }
  for (int m = tid; m < NM; m += 1024) {
    unsigned long long key = sk[m];
    int idx = (int)(key & 0xffffffffULL);
    fg_idx[b * NM + m] = idx;
    size_t src = ((size_t)b * NP + idx) * 3;
    size_t dst = ((size_t)b * NM + m) * 3;
    fg_xyz[dst + 0] = xyz[src + 0];
    fg_xyz[dst + 1] = xyz[src + 1];
    fg_xyz[dst + 2] = xyz[src + 2];
  }
}

// ---------- vote branch: gathered GEMM -> vh, reg head, clip, ctr points ----------
__global__ __launch_bounds__(256) void vote_kernel(
    const float* __restrict__ features, const int* __restrict__ fg_idx,
    const float* __restrict__ w1t, const float* __restrict__ scale1,
    const float* __restrict__ bias1, const float* __restrict__ rw,
    const float* __restrict__ rb, const float* __restrict__ fg_xyz,
    float* __restrict__ vh, float* __restrict__ offs, float* __restrict__ fg_ctr) {
  __shared__ float wt[32][128];
  __shared__ float ft[32][64];
  __shared__ float hl[128][65];
  __shared__ int idx_l[64];
  int b = blockIdx.y;
  int m0 = blockIdx.x * 64;
  int tid = threadIdx.x;
  int ro = tid >> 4, rc = tid & 15;
  const float* fb = features + (size_t)b * NC * NP;
  if (tid < 64) idx_l[tid] = fg_idx[b * NM + m0 + tid];
  __syncthreads();
  float acc[8][4] = {};
  for (int kc = 0; kc < NC; kc += 32) {
    for (int q = tid; q < 4096; q += 256) {
      int kk = q >> 7, o = q & 127;
      wt[kk][o] = w1t[(kc + kk) * NH + o];
    }
    for (int q = tid; q < 2048; q += 256) {
      int kk = q >> 6, mm = q & 63;
      ft[kk][mm] = fb[(size_t)(kc + kk) * NP + idx_l[mm]];
    }
    __syncthreads();
#pragma unroll
    for (int kk = 0; kk < 32; ++kk) {
      float wv[8], fv[4];
#pragma unroll
      for (int i = 0; i < 8; ++i) wv[i] = wt[kk][ro * 8 + i];
#pragma unroll
      for (int j = 0; j < 4; ++j) fv[j] = ft[kk][rc * 4 + j];
#pragma unroll
      for (int i = 0; i < 8; ++i)
#pragma unroll
        for (int j = 0; j < 4; ++j) acc[i][j] = fmaf(wv[i], fv[j], acc[i][j]);
    }
    __syncthreads();
  }
#pragma unroll
  for (int i = 0; i < 8; ++i) {
    int o = ro * 8 + i;
    float sc = scale1[o], bi = bias1[o];
#pragma unroll
    for (int j = 0; j < 4; ++j) {
      float h = fmaxf(fmaf(acc[i][j], sc, bi), 0.0f);
      hl[o][rc * 4 + j] = h;
      vh[((size_t)b * NH + o) * NM + m0 + rc * 4 + j] = h;
    }
  }
  __syncthreads();
  if (tid < 64) {
    int m = m0 + tid;
    const float MT[3] = {3.0f, 3.0f, 2.0f};
#pragma unroll
    for (int r = 0; r < 3; ++r) {
      float a = 0.0f;
      for (int o = 0; o < NH; ++o) a = fmaf(rw[r * NH + o], hl[o][tid], a);
      a += rb[r];
      a = fminf(fmaxf(a, -MT[r]), MT[r]);
      size_t p = ((size_t)b * NM + m) * 3 + r;
      offs[p] = a;
      fg_ctr[p] = __fadd_rn(fg_xyz[p], a);
    }
  }
}

// ---------- D-FPS: TWO independent problems per block (ori & ctr of one batch),
// interleaved in one loop sharing the barrier; exact np semantics ----------
#define PPT 8
__device__ __forceinline__ void fps_update8(
    const v2f* x, const v2f* y, const v2f* z, v2f* d,
    float sx, float sy, float sz, int base_idx, float& bd, int& bc) {
#pragma clang fp contract(off)
  v2f sxv, syv, szv;
  sxv.x = sx; sxv.y = sx;
  syv.x = sy; syv.y = sy;
  szv.x = sz; szv.y = sz;
  bd = -1.0f;
  bc = base_idx;
#pragma unroll
  for (int j = 0; j < 4; ++j) {
    v2f dx = x[j] - sxv, dy = y[j] - syv, dz = z[j] - szv;
    v2f dd = (dx * dx + dy * dy) + dz * dz;  // rn, np association
    v2f nd;
    nd.x = fminf(d[j].x, dd.x);
    nd.y = fminf(d[j].y, dd.y);
    d[j] = nd;
    if (j == 0) {
      bd = nd.x; bc = base_idx;
      bool g = nd.y > bd; bd = g ? nd.y : bd; bc = g ? base_idx + 1 : bc;
    } else {
      bool g0 = nd.x > bd; bd = g0 ? nd.x : bd; bc = g0 ? base_idx + 2 * j : bc;
      bool g1 = nd.y > bd; bd = g1 ? nd.y : bd; bc = g1 ? base_idx + 2 * j + 1 : bc;
    }
  }
}

__global__ __launch_bounds__(512) void fps_kernel(
    const float* __restrict__ fg_xyz, const float* __restrict__ fg_ctr,
    int* __restrict__ ori_idx, int* __restrict__ ctr_idx) {
#pragma clang fp contract(off)
  __shared__ float pxA[NM], pyA[NM], pzA[NM];  // 48 KB
  __shared__ float pxB[NM], pyB[NM], pzB[NM];  // 48 KB
  __shared__ unsigned long long wkeyA[2][8], wkeyB[2][8];
  int b = blockIdx.x;
  const float* PA = fg_xyz + (size_t)b * NM * 3;
  const float* PB = fg_ctr + (size_t)b * NM * 3;
  int* OA = ori_idx + b * NS;
  int* OB = ctr_idx + b * NS;
  int tid = threadIdx.x;
  for (int m = tid; m < NM; m += 512) {
    pxA[m] = PA[m * 3 + 0]; pyA[m] = PA[m * 3 + 1]; pzA[m] = PA[m * 3 + 2];
    pxB[m] = PB[m * 3 + 0]; pyB[m] = PB[m * 3 + 1]; pzB[m] = PB[m * 3 + 2];
  }
  __syncthreads();
  v2f xA[4], yA[4], zA[4], dA[4], xB[4], yB[4], zB[4], dB[4];
  int base_idx = tid * PPT;
#pragma unroll
  for (int j = 0; j < 4; ++j) {
    int m0 = base_idx + 2 * j, m1 = m0 + 1;
    v2f t;
    t.x = pxA[m0]; t.y = pxA[m1]; xA[j] = t;
    t.x = pyA[m0]; t.y = pyA[m1]; yA[j] = t;
    t.x = pzA[m0]; t.y = pzA[m1]; zA[j] = t;
    t.x = pxB[m0]; t.y = pxB[m1]; xB[j] = t;
    t.x = pyB[m0]; t.y = pyB[m1]; yB[j] = t;
    t.x = pzB[m0]; t.y = pzB[m1]; zB[j] = t;
    t.x = 3.402823466e38f; t.y = 3.402823466e38f;  // fmin(FLT_MAX,d0)==d0
    dA[j] = t; dB[j] = t;
  }
  if (tid == 0) { OA[0] = 0; OB[0] = 0; }
  int lane = tid & 63, wave = tid >> 6;
  float sxA = pxA[0], syA = pyA[0], szA = pzA[0];
  float sxB = pxB[0], syB = pyB[0], szB = pzB[0];
  for (int it = 1; it < NS; ++it) {
    // --- problem A: update + local argmax + wave reduce ---
    float bdA; int bcA;
    fps_update8(xA, yA, zA, dA, sxA, syA, szA, base_idx, bdA, bcA);
    float wmA = wave_max_dpp(bdA);
    unsigned long long mA = __ballot(bdA == wmA);
    int wlA = __ffsll((long long)mA) - 1;
    if (lane == wlA)
      wkeyA[it & 1][wave] =
          (((unsigned long long)__float_as_uint(bdA)) << 32) | (unsigned)(4095 - bcA);
    // --- problem B: independent chain, overlaps A's stalls ---
    float bdB; int bcB;
    fps_update8(xB, yB, zB, dB, sxB, syB, szB, base_idx, bdB, bcB);
    float wmB = wave_max_dpp(bdB);
    unsigned long long mB = __ballot(bdB == wmB);
    int wlB = __ffsll((long long)mB) - 1;
    if (lane == wlB)
      wkeyB[it & 1][wave] =
          (((unsigned long long)__float_as_uint(bdB)) << 32) | (unsigned)(4095 - bcB);
    __syncthreads();
    // cross-wave reduce, lane-distributed (slot = lane&7), 3-step DPP u64 max
    unsigned long long kA = wkeyA[it & 1][lane & 7];
    unsigned long long kB = wkeyB[it & 1][lane & 7];
    { unsigned long long o = dpp64<0xB1>(kA);  if (o > kA) kA = o; }
    { unsigned long long o = dpp64<0xB1>(kB);  if (o > kB) kB = o; }
    { unsigned long long o = dpp64<0x4E>(kA);  if (o > kA) kA = o; }
    { unsigned long long o = dpp64<0x4E>(kB);  if (o > kB) kB = o; }
    { unsigned long long o = dpp64<0x141>(kA); if (o > kA) kA = o; }
    { unsigned long long o = dpp64<0x141>(kB); if (o > kB) kB = o; }
    int selA = 4095 - (int)(kA & 0xffffffffULL);
    int selB = 4095 - (int)(kB & 0xffffffffULL);
    if (tid == 0) { OA[it] = selA; OB[it] = selB; }
    sxA = pxA[selA]; syA = pyA[selA]; szA = pzA[selA];  // broadcast reads
    sxB = pxB[selB]; syB = pyB[selB]; szB = pzB[selB];
  }
}

// ---------- agg_feat output ----------
__global__ __launch_bounds__(256) void feat_out_kernel(
    const float* __restrict__ vh, const float* __restrict__ features,
    const int* __restrict__ fg_idx, const int* __restrict__ ori_idx,
    const int* __restrict__ ctr_idx, float* __restrict__ out_feat) {
  int b = blockIdx.z;
  int o = blockIdx.y * 4 + (threadIdx.x >> 6);
  int s = blockIdx.x * 64 + (threadIdx.x & 63);
  float val;
  if (s < NS) {
    int i = ctr_idx[b * NS + s];
    val = vh[((size_t)b * NH + o) * NM + i];
  } else {
    int i = ori_idx[b * NS + (s - NS)];
    int g = fg_idx[b * NM + i];
    val = features[((size_t)b * NC + o) * NP + g];
  }
  out_feat[((size_t)b * NH + o) * (2 * NS) + s] = val;
}

// ---------- xyz / offset / origin outputs ----------
__global__ __launch_bounds__(256) void xyz_out_kernel(
    const float* __restrict__ fg_xyz, const float* __restrict__ fg_ctr,
    const float* __restrict__ offs, const int* __restrict__ ori_idx,
    const int* __restrict__ ctr_idx, float* __restrict__ out_agg,
    float* __restrict__ out_cxyz, float* __restrict__ out_coff,
    float* __restrict__ out_corg) {
  int b = blockIdx.y;
  int s = blockIdx.x * 256 + threadIdx.x;  // 0..2047
  if (s < NS) {
    int i = ctr_idx[b * NS + s];
    size_t src = ((size_t)b * NM + i) * 3;
    size_t d_agg = ((size_t)b * 2 * NS + s) * 3;
    size_t d_s = ((size_t)b * NS + s) * 3;
#pragma unroll
    for (int r = 0; r < 3; ++r) {
      float c = fg_ctr[src + r];
      out_agg[d_agg + r] = c;
      out_cxyz[d_s + r] = c;
      out_coff[d_s + r] = offs[src + r];
      out_corg[d_s + r] = fg_xyz[src + r];
    }
  } else {
    int i = ori_idx[b * NS + (s - NS)];
    size_t src = ((size_t)b * NM + i) * 3;
    size_t d_agg = ((size_t)b * 2 * NS + s) * 3;
#pragma unroll
    for (int r = 0; r < 3; ++r) out_agg[d_agg + r] = fg_xyz[src + r];
  }
}

extern "C" void kernel_launch(void* const* d_in, const int* in_sizes, int n_in,
                              void* d_out, int out_size, void* d_ws, size_t ws_size,
                              hipStream_t stream) {
  const float* xyz = (const float*)d_in[0];
  const float* features = (const float*)d_in[1];
  const float* seg_w1 = (const float*)d_in[2];
  const float* seg_scale1 = (const float*)d_in[3];
  const float* seg_bias1 = (const float*)d_in[4];
  const float* seg_w2 = (const float*)d_in[5];
  const float* seg_b2 = (const float*)d_in[6];
  const float* vote_w1 = (const float*)d_in[7];
  const float* vote_scale1 = (const float*)d_in[8];
  const float* vote_bias1 = (const float*)d_in[9];
  const float* reg_w = (const float*)d_in[10];
  const float* reg_b = (const float*)d_in[11];
  float* out = (float*)d_out;

  char* ws = (char*)d_ws;
  unsigned long long* keys = (unsigned long long*)(ws + 0);  // 1,048,576 B
  int* fg_idx = (int*)(ws + 1048576);                        // 131,072 B
  float* fg_xyz = (float*)(ws + 1179648);                    // 393,216 B
  float* fg_ctr = (float*)(ws + 1572864);                    // 393,216 B
  float* offs = (float*)(ws + 1966080);                      // 393,216 B
  int* ori_idx = (int*)(ws + 2359296);                       // 32,768 B
  int* ctr_idx = (int*)(ws + 2392064);                       // 32,768 B
  float* vh = (float*)(ws + 2424832);                        // 16,777,216 B
  float* w1t_s = (float*)(ws + 19202048);                    // 131,072 B
  float* w1t_v = (float*)(ws + 19333120);                    // 131,072 B (end 19,464,192)

  // outputs (reference return order), seg is [B,128,N]:
  float* out_agg_xyz = out;                  // [8,2048,3]      @ 0
  float* out_agg_feat = out + 49152;         // [8,128,2048]    @ 49152
  float* out_ctr_xyz = out + 2146304;        // [8,1024,3]      @ 2146304
  float* out_ctr_off = out + 2170880;        // [8,1024,3]      @ 2170880
  float* out_ctr_org = out + 2195456;        // [8,1024,3]      @ 2195456
  float* out_seg = out + 2220032;            // [8,128,16384]   @ 2220032

  transpose_w_kernel<<<128, 256, 0, stream>>>(seg_w1, vote_w1, w1t_s, w1t_v);
  seg_kernel<<<dim3(NP / 64, NB), 256, 0, stream>>>(
      features, w1t_s, seg_scale1, seg_bias1, seg_w2, seg_b2, out_seg, keys);
  sort8k_kernel<<<2 * NB, 1024, 0, stream>>>(keys);
  merge_topk_kernel<<<NB, 1024, 0, stream>>>(keys, fg_idx, fg_xyz, xyz);
  vote_kernel<<<dim3(NM / 64, NB), 256, 0, stream>>>(
      features, fg_idx, w1t_v, vote_scale1, vote_bias1, reg_w, reg_b, fg_xyz,
      vh, offs, fg_ctr);
  // both point-sets of a batch inside ONE block: shared barrier, overlapped chains
  fps_kernel<<<NB, 512, 0, stream>>>(fg_xyz, fg_ctr, ori_idx, ctr_idx);
  feat_out_kernel<<<dim3(32, 32, NB), 256, 0, stream>>>(
      vh, features, fg_idx, ori_idx, ctr_idx, out_agg_feat);
  xyz_out_kernel<<<dim3(8, NB), 256, 0, stream>>>(
      fg_xyz, fg_ctr, offs, ori_idx, ctr_idx, out_agg_xyz, out_ctr_xyz,
      out_ctr_off, out_ctr_org);
}

// Round 8
// 1429.734 us; speedup vs baseline: 1.0711x; 1.0711x over previous
//
#include <hip/hip_runtime.h>

#define NB 8
#define NP 16384
#define NC 256
#define NH 128
#define NM 4096
#define NS 1024

typedef float v2f __attribute__((ext_vector_type(2)));

// ---------- helpers ----------
__device__ __forceinline__ unsigned long long make_key(float v, int n) {
  unsigned u = __float_as_uint(v);
  u = (u & 0x80000000u) ? ~u : (u | 0x80000000u);  // map float -> ascending uint
  unsigned d = ~u;                                 // descending
  return (((unsigned long long)d) << 32) | (unsigned)n;
}

// VALU-only 64-lane max (values >= 0), result broadcast via readlane(63).
__device__ __forceinline__ float wave_max_dpp(float v) {
#define DPPMAX(ctrl)                                                            \
  v = fmaxf(v, __int_as_float(__builtin_amdgcn_update_dpp(                      \
                 __float_as_int(v), __float_as_int(v), (ctrl), 0xf, 0xf, false)))
  DPPMAX(0xB1);   // quad_perm [1,0,3,2]  : xor 1
  DPPMAX(0x4E);   // quad_perm [2,3,0,1]  : xor 2
  DPPMAX(0x141);  // row_half_mirror
  DPPMAX(0x140);  // row_mirror
  DPPMAX(0x142);  // row_bcast15
  DPPMAX(0x143);  // row_bcast31
#undef DPPMAX
  return __int_as_float(__builtin_amdgcn_readlane(__float_as_int(v), 63));
}

// 64-bit DPP lane-shuffle (both halves), compile-time ctrl
template <int CTRL>
__device__ __forceinline__ unsigned long long dpp64(unsigned long long v) {
  int lo = (int)(unsigned)v, hi = (int)(unsigned)(v >> 32);
  lo = __builtin_amdgcn_update_dpp(lo, lo, CTRL, 0xf, 0xf, false);
  hi = __builtin_amdgcn_update_dpp(hi, hi, CTRL, 0xf, 0xf, false);
  return (((unsigned long long)(unsigned)hi) << 32) | (unsigned)lo;
}

// ---------- transpose [H,C] -> [C,H] for both MLP weights ----------
__global__ __launch_bounds__(256) void transpose_w_kernel(
    const float* __restrict__ wseg, const float* __restrict__ wvote,
    float* __restrict__ tseg, float* __restrict__ tvote) {
  int i = blockIdx.x * 256 + threadIdx.x;  // 0..32767
  int c = i >> 7, o = i & 127;
  tseg[i] = wseg[o * NC + c];
  tvote[i] = wvote[o * NC + c];
}

// ---------- seg branch ----------
__global__ __launch_bounds__(256) void seg_kernel(
    const float* __restrict__ features, const float* __restrict__ w1t,
    const float* __restrict__ scale1, const float* __restrict__ bias1,
    const float* __restrict__ w2, const float* __restrict__ b2,
    float* __restrict__ seg_out, unsigned long long* __restrict__ keys) {
  __shared__ float wt[32][128];
  __shared__ float ft[32][64];
  __shared__ float red[16][64];
  __shared__ float Ssh[64];
  __shared__ float w2sh[128];
  int b = blockIdx.y;
  int n0 = blockIdx.x * 64;
  int tid = threadIdx.x;
  int lane = tid & 63;
  int ro = tid >> 4, rc = tid & 15;
  float a0 = w2[lane], a1 = w2[lane + 64];
  float whi = fmaxf(a0, a1), wlo = fminf(a0, a1);
#pragma unroll
  for (int off = 32; off >= 1; off >>= 1) {
    whi = fmaxf(whi, __shfl_xor(whi, off, 64));
    wlo = fminf(wlo, __shfl_xor(wlo, off, 64));
  }
  if (tid < 128) w2sh[tid] = w2[tid];
  const float* fb = features + (size_t)b * NC * NP;
  float acc[8][4] = {};
  for (int kc = 0; kc < NC; kc += 32) {
    for (int q = tid; q < 4096; q += 256) {
      int kk = q >> 7, o = q & 127;
      wt[kk][o] = w1t[(kc + kk) * NH + o];
    }
    for (int q = tid; q < 2048; q += 256) {
      int kk = q >> 6, nn = q & 63;
      ft[kk][nn] = fb[(size_t)(kc + kk) * NP + n0 + nn];
    }
    __syncthreads();
#pragma unroll
    for (int kk = 0; kk < 32; ++kk) {
      float wv[8], fv[4];
#pragma unroll
      for (int i = 0; i < 8; ++i) wv[i] = wt[kk][ro * 8 + i];
#pragma unroll
      for (int j = 0; j < 4; ++j) fv[j] = ft[kk][rc * 4 + j];
#pragma unroll
      for (int i = 0; i < 8; ++i)
#pragma unroll
        for (int j = 0; j < 4; ++j) acc[i][j] = fmaf(wv[i], fv[j], acc[i][j]);
    }
    __syncthreads();
  }
  float part[4] = {};
#pragma unroll
  for (int i = 0; i < 8; ++i) {
    int o = ro * 8 + i;
    float sc = scale1[o], bi = bias1[o];
#pragma unroll
    for (int j = 0; j < 4; ++j) {
      float h = fmaxf(fmaf(acc[i][j], sc, bi), 0.0f);
      part[j] += h;
    }
  }
#pragma unroll
  for (int j = 0; j < 4; ++j) red[ro][rc * 4 + j] = part[j];
  __syncthreads();
  float b2v = b2[0];
  if (tid < 64) {
    float S = 0.0f;
#pragma unroll
    for (int r = 0; r < 16; ++r) S += red[r][tid];
    Ssh[tid] = S;
    float m = (S >= 0.0f ? whi * S : wlo * S) + b2v;
    float sig = 1.0f / (1.0f + expf(-m));
    int nn = n0 + tid;
    keys[(size_t)b * NP + nn] = make_key(sig, nn);
  }
  __syncthreads();
  int n = tid & 63, kg = tid >> 6;
  float S = Ssh[n];
  size_t base = ((size_t)b * 128 + (size_t)kg * 32) * NP + n0 + n;
#pragma unroll
  for (int kk = 0; kk < 32; ++kk)
    seg_out[base + (size_t)kk * NP] = fmaf(w2sh[kg * 32 + kk], S, b2v);
}

// ---------- bitonic sort of each 8192-key chunk (chunk0 asc, chunk1 desc) ----------
__global__ __launch_bounds__(1024) void sort8k_kernel(unsigned long long* __restrict__ keys) {
  __shared__ unsigned long long sk[8192];
  int chunk = blockIdx.x & 1, b = blockIdx.x >> 1;
  bool desc = (chunk == 1);
  unsigned long long* K = keys + (size_t)b * NP + chunk * 8192;
  int tid = threadIdx.x;
  for (int i = tid; i < 8192; i += 1024) sk[i] = K[i];
  __syncthreads();
  for (int k = 2; k <= 8192; k <<= 1) {
    for (int j = k >> 1; j > 0; j >>= 1) {
      for (int i = tid; i < 8192; i += 1024) {
        int ixj = i ^ j;
        if (ixj > i) {
          bool up = (((i & k) == 0) != desc);
          unsigned long long a = sk[i], c = sk[ixj];
          if ((a > c) == up) { sk[i] = c; sk[ixj] = a; }
        }
      }
      __syncthreads();
    }
  }
  for (int i = tid; i < 8192; i += 1024) K[i] = sk[i];
}

// ---------- bitonic merge of lower half: exact top-4096 in sorted order ----------
__global__ __launch_bounds__(1024) void merge_topk_kernel(
    const unsigned long long* __restrict__ keys, int* __restrict__ fg_idx,
    float* __restrict__ fg_xyz, const float* __restrict__ xyz) {
  __shared__ unsigned long long sk[8192];
  int b = blockIdx.x;
  const unsigned long long* K = keys + (size_t)b * NP;
  int tid = threadIdx.x;
  for (int i = tid; i < 8192; i += 1024) {
    unsigned long long a = K[i], c = K[i + 8192];
    sk[i] = (a < c) ? a : c;
  }
  __syncthreads();
  for (int j = 4096; j > 0; j >>= 1) {
    for (int i = tid; i < 8192; i += 1024) {
      int ixj = i ^ j;
      if (ixj > i) {
        unsigned long long a = sk[i], c = sk[ixj];
        if (a > c) { sk[i] = c; sk[ixj] = a; }
      }
    }
    __syncthreads();
  }
  for (int m = tid; m < NM; m += 1024) {
    unsigned long long key = sk[m];
    int idx = (int)(key & 0xffffffffULL);
    fg_idx[b * NM + m] = idx;
    size_t src = ((size_t)b * NP + idx) * 3;
    size_t dst = ((size_t)b * NM + m) * 3;
    fg_xyz[dst + 0] = xyz[src + 0];
    fg_xyz[dst + 1] = xyz[src + 1];
    fg_xyz[dst + 2] = xyz[src + 2];
  }
}

// ---------- vote branch: gathered GEMM -> vh, reg head, clip, ctr points ----------
__global__ __launch_bounds__(256) void vote_kernel(
    const float* __restrict__ features, const int* __restrict__ fg_idx,
    const float* __restrict__ w1t, const float* __restrict__ scale1,
    const float* __restrict__ bias1, const float* __restrict__ rw,
    const float* __restrict__ rb, const float* __restrict__ fg_xyz,
    float* __restrict__ vh, float* __restrict__ offs, float* __restrict__ fg_ctr) {
  __shared__ float wt[32][128];
  __shared__ float ft[32][64];
  __shared__ float hl[128][65];
  __shared__ int idx_l[64];
  int b = blockIdx.y;
  int m0 = blockIdx.x * 64;
  int tid = threadIdx.x;
  int ro = tid >> 4, rc = tid & 15;
  const float* fb = features + (size_t)b * NC * NP;
  if (tid < 64) idx_l[tid] = fg_idx[b * NM + m0 + tid];
  __syncthreads();
  float acc[8][4] = {};
  for (int kc = 0; kc < NC; kc += 32) {
    for (int q = tid; q < 4096; q += 256) {
      int kk = q >> 7, o = q & 127;
      wt[kk][o] = w1t[(kc + kk) * NH + o];
    }
    for (int q = tid; q < 2048; q += 256) {
      int kk = q >> 6, mm = q & 63;
      ft[kk][mm] = fb[(size_t)(kc + kk) * NP + idx_l[mm]];
    }
    __syncthreads();
#pragma unroll
    for (int kk = 0; kk < 32; ++kk) {
      float wv[8], fv[4];
#pragma unroll
      for (int i = 0; i < 8; ++i) wv[i] = wt[kk][ro * 8 + i];
#pragma unroll
      for (int j = 0; j < 4; ++j) fv[j] = ft[kk][rc * 4 + j];
#pragma unroll
      for (int i = 0; i < 8; ++i)
#pragma unroll
        for (int j = 0; j < 4; ++j) acc[i][j] = fmaf(wv[i], fv[j], acc[i][j]);
    }
    __syncthreads();
  }
#pragma unroll
  for (int i = 0; i < 8; ++i) {
    int o = ro * 8 + i;
    float sc = scale1[o], bi = bias1[o];
#pragma unroll
    for (int j = 0; j < 4; ++j) {
      float h = fmaxf(fmaf(acc[i][j], sc, bi), 0.0f);
      hl[o][rc * 4 + j] = h;
      vh[((size_t)b * NH + o) * NM + m0 + rc * 4 + j] = h;
    }
  }
  __syncthreads();
  if (tid < 64) {
    int m = m0 + tid;
    const float MT[3] = {3.0f, 3.0f, 2.0f};
#pragma unroll
    for (int r = 0; r < 3; ++r) {
      float a = 0.0f;
      for (int o = 0; o < NH; ++o) a = fmaf(rw[r * NH + o], hl[o][tid], a);
      a += rb[r];
      a = fminf(fmaxf(a, -MT[r]), MT[r]);
      size_t p = ((size_t)b * NM + m) * 3 + r;
      offs[p] = a;
      fg_ctr[p] = __fadd_rn(fg_xyz[p], a);
    }
  }
}

// ---------- D-FPS: 2 problems per block in SEPARATE WAVE GROUPS (TLP hiding).
// waves 0-7: ori, waves 8-15: ctr. Shared barrier; exact np semantics. ----------
#define PPT 8
__device__ __forceinline__ void fps_update8(
    const v2f* x, const v2f* y, const v2f* z, v2f* d,
    float sx, float sy, float sz, int base_idx, float& bd, int& bc) {
#pragma clang fp contract(off)
  v2f sxv, syv, szv;
  sxv.x = sx; sxv.y = sx;
  syv.x = sy; syv.y = sy;
  szv.x = sz; szv.y = sz;
  bd = -1.0f;
  bc = base_idx;
#pragma unroll
  for (int j = 0; j < 4; ++j) {
    v2f dx = x[j] - sxv, dy = y[j] - syv, dz = z[j] - szv;
    v2f dd = (dx * dx + dy * dy) + dz * dz;  // rn, np association
    v2f nd;
    nd.x = fminf(d[j].x, dd.x);
    nd.y = fminf(d[j].y, dd.y);
    d[j] = nd;
    if (j == 0) {
      bd = nd.x; bc = base_idx;
      bool g = nd.y > bd; bd = g ? nd.y : bd; bc = g ? base_idx + 1 : bc;
    } else {
      bool g0 = nd.x > bd; bd = g0 ? nd.x : bd; bc = g0 ? base_idx + 2 * j : bc;
      bool g1 = nd.y > bd; bd = g1 ? nd.y : bd; bc = g1 ? base_idx + 2 * j + 1 : bc;
    }
  }
}

__global__ __launch_bounds__(1024) void fps_kernel(
    const float* __restrict__ fg_xyz, const float* __restrict__ fg_ctr,
    int* __restrict__ ori_idx, int* __restrict__ ctr_idx) {
#pragma clang fp contract(off)
  __shared__ float px[2][NM], py[2][NM], pz[2][NM];  // 96 KB
  __shared__ unsigned long long wkey[2][2][8];       // [grp][buf][slot]
  int b = blockIdx.x;
  int tid = threadIdx.x;
  int grp = tid >> 9;    // 0: ori (waves 0-7), 1: ctr (waves 8-15)
  int ltid = tid & 511;  // thread id within the group
  const float* P = (grp == 0 ? fg_xyz : fg_ctr) + (size_t)b * NM * 3;
  int* O = (grp == 0 ? ori_idx : ctr_idx) + b * NS;
  for (int m = ltid; m < NM; m += 512) {
    px[grp][m] = P[m * 3 + 0];
    py[grp][m] = P[m * 3 + 1];
    pz[grp][m] = P[m * 3 + 2];
  }
  __syncthreads();
  v2f x2[4], y2[4], z2[4], d2[4];
  int base_idx = ltid * PPT;
#pragma unroll
  for (int j = 0; j < 4; ++j) {
    int m0 = base_idx + 2 * j, m1 = m0 + 1;
    v2f t;
    t.x = px[grp][m0]; t.y = px[grp][m1]; x2[j] = t;
    t.x = py[grp][m0]; t.y = py[grp][m1]; y2[j] = t;
    t.x = pz[grp][m0]; t.y = pz[grp][m1]; z2[j] = t;
    t.x = 3.402823466e38f; t.y = 3.402823466e38f;  // fmin(FLT_MAX,d0)==d0
    d2[j] = t;
  }
  if (ltid == 0) O[0] = 0;
  int lane = tid & 63, gwave = (tid >> 6) & 7;  // group-local wave 0..7
  float sx = px[grp][0], sy = py[grp][0], sz = pz[grp][0];
  for (int it = 1; it < NS; ++it) {
    // update 8 pts + local first-max (exact np order/rounding)
    float bd; int bc;
    fps_update8(x2, y2, z2, d2, sx, sy, sz, base_idx, bd, bc);
    // wave max on VALU (DPP), exact first-index tie-break via ballot
    float wm = wave_max_dpp(bd);
    unsigned long long msk = __ballot(bd == wm);
    int wl = __ffsll((long long)msk) - 1;
    if (lane == wl)
      wkey[grp][it & 1][gwave] =
          (((unsigned long long)__float_as_uint(bd)) << 32) | (unsigned)(4095 - bc);
    __syncthreads();
    // cross-wave reduce, lane-distributed (slot = lane&7), 3-step DPP u64 max
    unsigned long long k = wkey[grp][it & 1][lane & 7];
    { unsigned long long o = dpp64<0xB1>(k);  if (o > k) k = o; }   // xor 1
    { unsigned long long o = dpp64<0x4E>(k);  if (o > k) k = o; }   // xor 2
    { unsigned long long o = dpp64<0x141>(k); if (o > k) k = o; }   // half-mirror
    int sel = 4095 - (int)(k & 0xffffffffULL);
    if (ltid == 0) O[it] = sel;
    sx = px[grp][sel]; sy = py[grp][sel]; sz = pz[grp][sel];  // broadcast reads
  }
}

// ---------- agg_feat output ----------
__global__ __launch_bounds__(256) void feat_out_kernel(
    const float* __restrict__ vh, const float* __restrict__ features,
    const int* __restrict__ fg_idx, const int* __restrict__ ori_idx,
    const int* __restrict__ ctr_idx, float* __restrict__ out_feat) {
  int b = blockIdx.z;
  int o = blockIdx.y * 4 + (threadIdx.x >> 6);
  int s = blockIdx.x * 64 + (threadIdx.x & 63);
  float val;
  if (s < NS) {
    int i = ctr_idx[b * NS + s];
    val = vh[((size_t)b * NH + o) * NM + i];
  } else {
    int i = ori_idx[b * NS + (s - NS)];
    int g = fg_idx[b * NM + i];
    val = features[((size_t)b * NC + o) * NP + g];
  }
  out_feat[((size_t)b * NH + o) * (2 * NS) + s] = val;
}

// ---------- xyz / offset / origin outputs ----------
__global__ __launch_bounds__(256) void xyz_out_kernel(
    const float* __restrict__ fg_xyz, const float* __restrict__ fg_ctr,
    const float* __restrict__ offs, const int* __restrict__ ori_idx,
    const int* __restrict__ ctr_idx, float* __restrict__ out_agg,
    float* __restrict__ out_cxyz, float* __restrict__ out_coff,
    float* __restrict__ out_corg) {
  int b = blockIdx.y;
  int s = blockIdx.x * 256 + threadIdx.x;  // 0..2047
  if (s < NS) {
    int i = ctr_idx[b * NS + s];
    size_t src = ((size_t)b * NM + i) * 3;
    size_t d_agg = ((size_t)b * 2 * NS + s) * 3;
    size_t d_s = ((size_t)b * NS + s) * 3;
#pragma unroll
    for (int r = 0; r < 3; ++r) {
      float c = fg_ctr[src + r];
      out_agg[d_agg + r] = c;
      out_cxyz[d_s + r] = c;
      out_coff[d_s + r] = offs[src + r];
      out_corg[d_s + r] = fg_xyz[src + r];
    }
  } else {
    int i = ori_idx[b * NS + (s - NS)];
    size_t src = ((size_t)b * NM + i) * 3;
    size_t d_agg = ((size_t)b * 2 * NS + s) * 3;
#pragma unroll
    for (int r = 0; r < 3; ++r) out_agg[d_agg + r] = fg_xyz[src + r];
  }
}

extern "C" void kernel_launch(void* const* d_in, const int* in_sizes, int n_in,
                              void* d_out, int out_size, void* d_ws, size_t ws_size,
                              hipStream_t stream) {
  const float* xyz = (const float*)d_in[0];
  const float* features = (const float*)d_in[1];
  const float* seg_w1 = (const float*)d_in[2];
  const float* seg_scale1 = (const float*)d_in[3];
  const float* seg_bias1 = (const float*)d_in[4];
  const float* seg_w2 = (const float*)d_in[5];
  const float* seg_b2 = (const float*)d_in[6];
  const float* vote_w1 = (const float*)d_in[7];
  const float* vote_scale1 = (const float*)d_in[8];
  const float* vote_bias1 = (const float*)d_in[9];
  const float* reg_w = (const float*)d_in[10];
  const float* reg_b = (const float*)d_in[11];
  float* out = (float*)d_out;

  char* ws = (char*)d_ws;
  unsigned long long* keys = (unsigned long long*)(ws + 0);  // 1,048,576 B
  int* fg_idx = (int*)(ws + 1048576);                        // 131,072 B
  float* fg_xyz = (float*)(ws + 1179648);                    // 393,216 B
  float* fg_ctr = (float*)(ws + 1572864);                    // 393,216 B
  float* offs = (float*)(ws + 1966080);                      // 393,216 B
  int* ori_idx = (int*)(ws + 2359296);                       // 32,768 B
  int* ctr_idx = (int*)(ws + 2392064);                       // 32,768 B
  float* vh = (float*)(ws + 2424832);                        // 16,777,216 B
  float* w1t_s = (float*)(ws + 19202048);                    // 131,072 B
  float* w1t_v = (float*)(ws + 19333120);                    // 131,072 B (end 19,464,192)

  // outputs (reference return order), seg is [B,128,N]:
  float* out_agg_xyz = out;                  // [8,2048,3]      @ 0
  float* out_agg_feat = out + 49152;         // [8,128,2048]    @ 49152
  float* out_ctr_xyz = out + 2146304;        // [8,1024,3]      @ 2146304
  float* out_ctr_off = out + 2170880;        // [8,1024,3]      @ 2170880
  float* out_ctr_org = out + 2195456;        // [8,1024,3]      @ 2195456
  float* out_seg = out + 2220032;            // [8,128,16384]   @ 2220032

  transpose_w_kernel<<<128, 256, 0, stream>>>(seg_w1, vote_w1, w1t_s, w1t_v);
  seg_kernel<<<dim3(NP / 64, NB), 256, 0, stream>>>(
      features, w1t_s, seg_scale1, seg_bias1, seg_w2, seg_b2, out_seg, keys);
  sort8k_kernel<<<2 * NB, 1024, 0, stream>>>(keys);
  merge_topk_kernel<<<NB, 1024, 0, stream>>>(keys, fg_idx, fg_xyz, xyz);
  vote_kernel<<<dim3(NM / 64, NB), 256, 0, stream>>>(
      features, fg_idx, w1t_v, vote_scale1, vote_bias1, reg_w, reg_b, fg_xyz,
      vh, offs, fg_ctr);
  // 2 problems per block in separate wave groups: TLP hides the serial chain
  fps_kernel<<<NB, 1024, 0, stream>>>(fg_xyz, fg_ctr, ori_idx, ctr_idx);
  feat_out_kernel<<<dim3(32, 32, NB), 256, 0, stream>>>(
      vh, features, fg_idx, ori_idx, ctr_idx, out_agg_feat);
  xyz_out_kernel<<<dim3(8, NB), 256, 0, stream>>>(
      fg_xyz, fg_ctr, offs, ori_idx, ctr_idx, out_agg_xyz, out_ctr_xyz,
      out_ctr_off, out_ctr_org);
}

// Round 9
// 997.185 us; speedup vs baseline: 1.5356x; 1.4338x over previous
//
#include <hip/hip_runtime.h>

#define NB 8
#define NP 16384
#define NC 256
#define NH 128
#define NM 4096
#define NS 1024

typedef float v2f __attribute__((ext_vector_type(2)));

// ---------- helpers ----------
__device__ __forceinline__ unsigned long long make_key(float v, int n) {
  unsigned u = __float_as_uint(v);
  u = (u & 0x80000000u) ? ~u : (u | 0x80000000u);  // map float -> ascending uint
  unsigned d = ~u;                                 // descending
  return (((unsigned long long)d) << 32) | (unsigned)n;
}

// VALU-only 64-lane max (values >= 0), result broadcast via readlane(63).
__device__ __forceinline__ float wave_max_dpp(float v) {
#define DPPMAX(ctrl)                                                            \
  v = fmaxf(v, __int_as_float(__builtin_amdgcn_update_dpp(                      \
                 __float_as_int(v), __float_as_int(v), (ctrl), 0xf, 0xf, false)))
  DPPMAX(0xB1);   // quad_perm [1,0,3,2]  : xor 1
  DPPMAX(0x4E);   // quad_perm [2,3,0,1]  : xor 2
  DPPMAX(0x141);  // row_half_mirror
  DPPMAX(0x140);  // row_mirror
  DPPMAX(0x142);  // row_bcast15
  DPPMAX(0x143);  // row_bcast31
#undef DPPMAX
  return __int_as_float(__builtin_amdgcn_readlane(__float_as_int(v), 63));
}

// ---------- transpose [H,C] -> [C,H] for both MLP weights ----------
__global__ __launch_bounds__(256) void transpose_w_kernel(
    const float* __restrict__ wseg, const float* __restrict__ wvote,
    float* __restrict__ tseg, float* __restrict__ tvote) {
  int i = blockIdx.x * 256 + threadIdx.x;  // 0..32767
  int c = i >> 7, o = i & 127;
  tseg[i] = wseg[o * NC + c];
  tvote[i] = wvote[o * NC + c];
}

// ---------- seg branch ----------
__global__ __launch_bounds__(256) void seg_kernel(
    const float* __restrict__ features, const float* __restrict__ w1t,
    const float* __restrict__ scale1, const float* __restrict__ bias1,
    const float* __restrict__ w2, const float* __restrict__ b2,
    float* __restrict__ seg_out, unsigned long long* __restrict__ keys) {
  __shared__ float wt[32][128];
  __shared__ float ft[32][64];
  __shared__ float red[16][64];
  __shared__ float Ssh[64];
  __shared__ float w2sh[128];
  int b = blockIdx.y;
  int n0 = blockIdx.x * 64;
  int tid = threadIdx.x;
  int lane = tid & 63;
  int ro = tid >> 4, rc = tid & 15;
  float a0 = w2[lane], a1 = w2[lane + 64];
  float whi = fmaxf(a0, a1), wlo = fminf(a0, a1);
#pragma unroll
  for (int off = 32; off >= 1; off >>= 1) {
    whi = fmaxf(whi, __shfl_xor(whi, off, 64));
    wlo = fminf(wlo, __shfl_xor(wlo, off, 64));
  }
  if (tid < 128) w2sh[tid] = w2[tid];
  const float* fb = features + (size_t)b * NC * NP;
  float acc[8][4] = {};
  for (int kc = 0; kc < NC; kc += 32) {
    for (int q = tid; q < 4096; q += 256) {
      int kk = q >> 7, o = q & 127;
      wt[kk][o] = w1t[(kc + kk) * NH + o];
    }
    for (int q = tid; q < 2048; q += 256) {
      int kk = q >> 6, nn = q & 63;
      ft[kk][nn] = fb[(size_t)(kc + kk) * NP + n0 + nn];
    }
    __syncthreads();
#pragma unroll
    for (int kk = 0; kk < 32; ++kk) {
      float wv[8], fv[4];
#pragma unroll
      for (int i = 0; i < 8; ++i) wv[i] = wt[kk][ro * 8 + i];
#pragma unroll
      for (int j = 0; j < 4; ++j) fv[j] = ft[kk][rc * 4 + j];
#pragma unroll
      for (int i = 0; i < 8; ++i)
#pragma unroll
        for (int j = 0; j < 4; ++j) acc[i][j] = fmaf(wv[i], fv[j], acc[i][j]);
    }
    __syncthreads();
  }
  float part[4] = {};
#pragma unroll
  for (int i = 0; i < 8; ++i) {
    int o = ro * 8 + i;
    float sc = scale1[o], bi = bias1[o];
#pragma unroll
    for (int j = 0; j < 4; ++j) {
      float h = fmaxf(fmaf(acc[i][j], sc, bi), 0.0f);
      part[j] += h;
    }
  }
#pragma unroll
  for (int j = 0; j < 4; ++j) red[ro][rc * 4 + j] = part[j];
  __syncthreads();
  float b2v = b2[0];
  if (tid < 64) {
    float S = 0.0f;
#pragma unroll
    for (int r = 0; r < 16; ++r) S += red[r][tid];
    Ssh[tid] = S;
    float m = (S >= 0.0f ? whi * S : wlo * S) + b2v;
    float sig = 1.0f / (1.0f + expf(-m));
    int nn = n0 + tid;
    keys[(size_t)b * NP + nn] = make_key(sig, nn);
  }
  __syncthreads();
  int n = tid & 63, kg = tid >> 6;
  float S = Ssh[n];
  size_t base = ((size_t)b * 128 + (size_t)kg * 32) * NP + n0 + n;
#pragma unroll
  for (int kk = 0; kk < 32; ++kk)
    seg_out[base + (size_t)kk * NP] = fmaf(w2sh[kg * 32 + kk], S, b2v);
}

// ---------- bitonic sort of each 8192-key chunk (chunk0 asc, chunk1 desc) ----------
__global__ __launch_bounds__(1024) void sort8k_kernel(unsigned long long* __restrict__ keys) {
  __shared__ unsigned long long sk[8192];
  int chunk = blockIdx.x & 1, b = blockIdx.x >> 1;
  bool desc = (chunk == 1);
  unsigned long long* K = keys + (size_t)b * NP + chunk * 8192;
  int tid = threadIdx.x;
  for (int i = tid; i < 8192; i += 1024) sk[i] = K[i];
  __syncthreads();
  for (int k = 2; k <= 8192; k <<= 1) {
    for (int j = k >> 1; j > 0; j >>= 1) {
      for (int i = tid; i < 8192; i += 1024) {
        int ixj = i ^ j;
        if (ixj > i) {
          bool up = (((i & k) == 0) != desc);
          unsigned long long a = sk[i], c = sk[ixj];
          if ((a > c) == up) { sk[i] = c; sk[ixj] = a; }
        }
      }
      __syncthreads();
    }
  }
  for (int i = tid; i < 8192; i += 1024) K[i] = sk[i];
}

// ---------- bitonic merge of lower half: exact top-4096 in sorted order ----------
__global__ __launch_bounds__(1024) void merge_topk_kernel(
    const unsigned long long* __restrict__ keys, int* __restrict__ fg_idx,
    float* __restrict__ fg_xyz, const float* __restrict__ xyz) {
  __shared__ unsigned long long sk[8192];
  int b = blockIdx.x;
  const unsigned long long* K = keys + (size_t)b * NP;
  int tid = threadIdx.x;
  for (int i = tid; i < 8192; i += 1024) {
    unsigned long long a = K[i], c = K[i + 8192];
    sk[i] = (a < c) ? a : c;
  }
  __syncthreads();
  for (int j = 4096; j > 0; j >>= 1) {
    for (int i = tid; i < 8192; i += 1024) {
      int ixj = i ^ j;
      if (ixj > i) {
        unsigned long long a = sk[i], c = sk[ixj];
        if (a > c) { sk[i] = c; sk[ixj] = a; }
      }
    }
    __syncthreads();
  }
  for (int m = tid; m < NM; m += 1024) {
    unsigned long long key = sk[m];
    int idx = (int)(key & 0xffffffffULL);
    fg_idx[b * NM + m] = idx;
    size_t src = ((size_t)b * NP + idx) * 3;
    size_t dst = ((size_t)b * NM + m) * 3;
    fg_xyz[dst + 0] = xyz[src + 0];
    fg_xyz[dst + 1] = xyz[src + 1];
    fg_xyz[dst + 2] = xyz[src + 2];
  }
}

// ---------- vote branch: gathered GEMM -> vh, reg head, clip, ctr points ----------
__global__ __launch_bounds__(256) void vote_kernel(
    const float* __restrict__ features, const int* __restrict__ fg_idx,
    const float* __restrict__ w1t, const float* __restrict__ scale1,
    const float* __restrict__ bias1, const float* __restrict__ rw,
    const float* __restrict__ rb, const float* __restrict__ fg_xyz,
    float* __restrict__ vh, float* __restrict__ offs, float* __restrict__ fg_ctr) {
  __shared__ float wt[32][128];
  __shared__ float ft[32][64];
  __shared__ float hl[128][65];
  __shared__ int idx_l[64];
  int b = blockIdx.y;
  int m0 = blockIdx.x * 64;
  int tid = threadIdx.x;
  int ro = tid >> 4, rc = tid & 15;
  const float* fb = features + (size_t)b * NC * NP;
  if (tid < 64) idx_l[tid] = fg_idx[b * NM + m0 + tid];
  __syncthreads();
  float acc[8][4] = {};
  for (int kc = 0; kc < NC; kc += 32) {
    for (int q = tid; q < 4096; q += 256) {
      int kk = q >> 7, o = q & 127;
      wt[kk][o] = w1t[(kc + kk) * NH + o];
    }
    for (int q = tid; q < 2048; q += 256) {
      int kk = q >> 6, mm = q & 63;
      ft[kk][mm] = fb[(size_t)(kc + kk) * NP + idx_l[mm]];
    }
    __syncthreads();
#pragma unroll
    for (int kk = 0; kk < 32; ++kk) {
      float wv[8], fv[4];
#pragma unroll
      for (int i = 0; i < 8; ++i) wv[i] = wt[kk][ro * 8 + i];
#pragma unroll
      for (int j = 0; j < 4; ++j) fv[j] = ft[kk][rc * 4 + j];
#pragma unroll
      for (int i = 0; i < 8; ++i)
#pragma unroll
        for (int j = 0; j < 4; ++j) acc[i][j] = fmaf(wv[i], fv[j], acc[i][j]);
    }
    __syncthreads();
  }
#pragma unroll
  for (int i = 0; i < 8; ++i) {
    int o = ro * 8 + i;
    float sc = scale1[o], bi = bias1[o];
#pragma unroll
    for (int j = 0; j < 4; ++j) {
      float h = fmaxf(fmaf(acc[i][j], sc, bi), 0.0f);
      hl[o][rc * 4 + j] = h;
      vh[((size_t)b * NH + o) * NM + m0 + rc * 4 + j] = h;
    }
  }
  __syncthreads();
  if (tid < 64) {
    int m = m0 + tid;
    const float MT[3] = {3.0f, 3.0f, 2.0f};
#pragma unroll
    for (int r = 0; r < 3; ++r) {
      float a = 0.0f;
      for (int o = 0; o < NH; ++o) a = fmaf(rw[r * NH + o], hl[o][tid], a);
      a += rb[r];
      a = fminf(fmaxf(a, -MT[r]), MT[r]);
      size_t p = ((size_t)b * NM + m) * 3 + r;
      offs[p] = a;
      fg_ctr[p] = __fadd_rn(fg_xyz[p], a);
    }
  }
}

// ---------- D-FPS: R5 structure, 4 waves x 16 pts/lane, LDS sel_list,
// 4-slot key reduce (one 32B broadcast read + 3 compares); exact np semantics ----
#define PPT 16
__global__ __launch_bounds__(256) void fps_kernel(
    const float* __restrict__ fg_xyz, const float* __restrict__ fg_ctr,
    int* __restrict__ ori_idx, int* __restrict__ ctr_idx) {
#pragma clang fp contract(off)
  __shared__ float px[NM], py[NM], pz[NM];          // 48 KB
  __shared__ __align__(32) unsigned long long wkey[2][4];
  __shared__ int sel_list[NS];
  int set = blockIdx.x & 1, b = blockIdx.x >> 1;
  const float* P = (set == 0 ? fg_xyz : fg_ctr) + (size_t)b * NM * 3;
  int* O = (set == 0 ? ori_idx : ctr_idx) + b * NS;
  int tid = threadIdx.x;
  for (int m = tid; m < NM; m += 256) {
    px[m] = P[m * 3 + 0];
    py[m] = P[m * 3 + 1];
    pz[m] = P[m * 3 + 2];
  }
  __syncthreads();
  v2f x2[8], y2[8], z2[8], d2[8];
  int base_idx = tid * PPT;
#pragma unroll
  for (int j = 0; j < 8; ++j) {
    int m0 = base_idx + 2 * j, m1 = m0 + 1;
    v2f t;
    t.x = px[m0]; t.y = px[m1]; x2[j] = t;
    t.x = py[m0]; t.y = py[m1]; y2[j] = t;
    t.x = pz[m0]; t.y = pz[m1]; z2[j] = t;
    t.x = 3.402823466e38f; t.y = 3.402823466e38f;  // fmin(FLT_MAX,d0)==d0
    d2[j] = t;
  }
  if (tid == 0) sel_list[0] = 0;
  int lane = tid & 63, wave = tid >> 6;  // 4 waves
  float sx = px[0], sy = py[0], sz = pz[0];
  for (int it = 1; it < NS; ++it) {
    v2f sxv, syv, szv;
    sxv.x = sx; sxv.y = sx;
    syv.x = sy; syv.y = sy;
    szv.x = sz; szv.y = sz;
    // fused update (min with dist to prev selection) + local first-max, np order
    float bd = -1.0f;
    int bc = base_idx;
#pragma unroll
    for (int j = 0; j < 8; ++j) {
      v2f dx = x2[j] - sxv, dy = y2[j] - syv, dz = z2[j] - szv;
      v2f dd = (dx * dx + dy * dy) + dz * dz;  // rn, np association
      v2f nd;
      nd.x = fminf(d2[j].x, dd.x);
      nd.y = fminf(d2[j].y, dd.y);
      d2[j] = nd;
      if (j == 0) {
        bd = nd.x; bc = base_idx;
        bool g = nd.y > bd; bd = g ? nd.y : bd; bc = g ? base_idx + 1 : bc;
      } else {
        bool g0 = nd.x > bd; bd = g0 ? nd.x : bd; bc = g0 ? base_idx + 2 * j : bc;
        bool g1 = nd.y > bd; bd = g1 ? nd.y : bd; bc = g1 ? base_idx + 2 * j + 1 : bc;
      }
    }
    // wave max on VALU (DPP), exact first-index tie-break via ballot
    float wm = wave_max_dpp(bd);
    unsigned long long msk = __ballot(bd == wm);
    int wl = __ffsll((long long)msk) - 1;
    if (lane == wl)
      wkey[it & 1][wave] =
          (((unsigned long long)__float_as_uint(bd)) << 32) | (unsigned)(4095 - bc);
    __syncthreads();
    // 4-slot reduce: one 32B broadcast read + 3 u64 compares
    const ulonglong2* wk = (const ulonglong2*)&wkey[it & 1][0];
    ulonglong2 q0 = wk[0], q1 = wk[1];
    unsigned long long m0 = q0.x > q0.y ? q0.x : q0.y;
    unsigned long long m1 = q1.x > q1.y ? q1.x : q1.y;
    unsigned long long km = m0 > m1 ? m0 : m1;
    int sel = 4095 - (int)(km & 0xffffffffULL);
    if (tid == 0) sel_list[it] = sel;  // LDS, not global (vmcnt-free barrier)
    sx = px[sel]; sy = py[sel]; sz = pz[sel];  // broadcast reads
  }
  __syncthreads();
  for (int s2 = tid; s2 < NS; s2 += 256) O[s2] = sel_list[s2];
}

// ---------- agg_feat output ----------
__global__ __launch_bounds__(256) void feat_out_kernel(
    const float* __restrict__ vh, const float* __restrict__ features,
    const int* __restrict__ fg_idx, const int* __restrict__ ori_idx,
    const int* __restrict__ ctr_idx, float* __restrict__ out_feat) {
  int b = blockIdx.z;
  int o = blockIdx.y * 4 + (threadIdx.x >> 6);
  int s = blockIdx.x * 64 + (threadIdx.x & 63);
  float val;
  if (s < NS) {
    int i = ctr_idx[b * NS + s];
    val = vh[((size_t)b * NH + o) * NM + i];
  } else {
    int i = ori_idx[b * NS + (s - NS)];
    int g = fg_idx[b * NM + i];
    val = features[((size_t)b * NC + o) * NP + g];
  }
  out_feat[((size_t)b * NH + o) * (2 * NS) + s] = val;
}

// ---------- xyz / offset / origin outputs ----------
__global__ __launch_bounds__(256) void xyz_out_kernel(
    const float* __restrict__ fg_xyz, const float* __restrict__ fg_ctr,
    const float* __restrict__ offs, const int* __restrict__ ori_idx,
    const int* __restrict__ ctr_idx, float* __restrict__ out_agg,
    float* __restrict__ out_cxyz, float* __restrict__ out_coff,
    float* __restrict__ out_corg) {
  int b = blockIdx.y;
  int s = blockIdx.x * 256 + threadIdx.x;  // 0..2047
  if (s < NS) {
    int i = ctr_idx[b * NS + s];
    size_t src = ((size_t)b * NM + i) * 3;
    size_t d_agg = ((size_t)b * 2 * NS + s) * 3;
    size_t d_s = ((size_t)b * NS + s) * 3;
#pragma unroll
    for (int r = 0; r < 3; ++r) {
      float c = fg_ctr[src + r];
      out_agg[d_agg + r] = c;
      out_cxyz[d_s + r] = c;
      out_coff[d_s + r] = offs[src + r];
      out_corg[d_s + r] = fg_xyz[src + r];
    }
  } else {
    int i = ori_idx[b * NS + (s - NS)];
    size_t src = ((size_t)b * NM + i) * 3;
    size_t d_agg = ((size_t)b * 2 * NS + s) * 3;
#pragma unroll
    for (int r = 0; r < 3; ++r) out_agg[d_agg + r] = fg_xyz[src + r];
  }
}

extern "C" void kernel_launch(void* const* d_in, const int* in_sizes, int n_in,
                              void* d_out, int out_size, void* d_ws, size_t ws_size,
                              hipStream_t stream) {
  const float* xyz = (const float*)d_in[0];
  const float* features = (const float*)d_in[1];
  const float* seg_w1 = (const float*)d_in[2];
  const float* seg_scale1 = (const float*)d_in[3];
  const float* seg_bias1 = (const float*)d_in[4];
  const float* seg_w2 = (const float*)d_in[5];
  const float* seg_b2 = (const float*)d_in[6];
  const float* vote_w1 = (const float*)d_in[7];
  const float* vote_scale1 = (const float*)d_in[8];
  const float* vote_bias1 = (const float*)d_in[9];
  const float* reg_w = (const float*)d_in[10];
  const float* reg_b = (const float*)d_in[11];
  float* out = (float*)d_out;

  char* ws = (char*)d_ws;
  unsigned long long* keys = (unsigned long long*)(ws + 0);  // 1,048,576 B
  int* fg_idx = (int*)(ws + 1048576);                        // 131,072 B
  float* fg_xyz = (float*)(ws + 1179648);                    // 393,216 B
  float* fg_ctr = (float*)(ws + 1572864);                    // 393,216 B
  float* offs = (float*)(ws + 1966080);                      // 393,216 B
  int* ori_idx = (int*)(ws + 2359296);                       // 32,768 B
  int* ctr_idx = (int*)(ws + 2392064);                       // 32,768 B
  float* vh = (float*)(ws + 2424832);                        // 16,777,216 B
  float* w1t_s = (float*)(ws + 19202048);                    // 131,072 B
  float* w1t_v = (float*)(ws + 19333120);                    // 131,072 B (end 19,464,192)

  // outputs (reference return order), seg is [B,128,N]:
  float* out_agg_xyz = out;                  // [8,2048,3]      @ 0
  float* out_agg_feat = out + 49152;         // [8,128,2048]    @ 49152
  float* out_ctr_xyz = out + 2146304;        // [8,1024,3]      @ 2146304
  float* out_ctr_off = out + 2170880;        // [8,1024,3]      @ 2170880
  float* out_ctr_org = out + 2195456;        // [8,1024,3]      @ 2195456
  float* out_seg = out + 2220032;            // [8,128,16384]   @ 2220032

  transpose_w_kernel<<<128, 256, 0, stream>>>(seg_w1, vote_w1, w1t_s, w1t_v);
  seg_kernel<<<dim3(NP / 64, NB), 256, 0, stream>>>(
      features, w1t_s, seg_scale1, seg_bias1, seg_w2, seg_b2, out_seg, keys);
  sort8k_kernel<<<2 * NB, 1024, 0, stream>>>(keys);
  merge_topk_kernel<<<NB, 1024, 0, stream>>>(keys, fg_idx, fg_xyz, xyz);
  vote_kernel<<<dim3(NM / 64, NB), 256, 0, stream>>>(
      features, fg_idx, w1t_v, vote_scale1, vote_bias1, reg_w, reg_b, fg_xyz,
      vh, offs, fg_ctr);
  // one problem per block, 16 blocks in ONE dispatch (R5 structure, 4 waves)
  fps_kernel<<<16, 256, 0, stream>>>(fg_xyz, fg_ctr, ori_idx, ctr_idx);
  feat_out_kernel<<<dim3(32, 32, NB), 256, 0, stream>>>(
      vh, features, fg_idx, ori_idx, ctr_idx, out_agg_feat);
  xyz_out_kernel<<<dim3(8, NB), 256, 0, stream>>>(
      fg_xyz, fg_ctr, offs, ori_idx, ctr_idx, out_agg_xyz, out_ctr_xyz,
      out_ctr_off, out_ctr_org);
}

// Round 10
// 970.029 us; speedup vs baseline: 1.5786x; 1.0280x over previous
//
#include <hip/hip_runtime.h>

#define NB 8
#define NP 16384
#define NC 256
#define NH 128
#define NM 4096
#define NS 1024

typedef float v2f __attribute__((ext_vector_type(2)));

// ---------- helpers ----------
__device__ __forceinline__ unsigned long long make_key(float v, int n) {
  unsigned u = __float_as_uint(v);
  u = (u & 0x80000000u) ? ~u : (u | 0x80000000u);  // map float -> ascending uint
  unsigned d = ~u;                                 // descending
  return (((unsigned long long)d) << 32) | (unsigned)n;
}

// VALU-only 64-lane max (values >= 0), result broadcast via readlane(63).
__device__ __forceinline__ float wave_max_dpp(float v) {
#define DPPMAX(ctrl)                                                            \
  v = fmaxf(v, __int_as_float(__builtin_amdgcn_update_dpp(                      \
                 __float_as_int(v), __float_as_int(v), (ctrl), 0xf, 0xf, false)))
  DPPMAX(0xB1);   // quad_perm [1,0,3,2]  : xor 1
  DPPMAX(0x4E);   // quad_perm [2,3,0,1]  : xor 2
  DPPMAX(0x141);  // row_half_mirror
  DPPMAX(0x140);  // row_mirror
  DPPMAX(0x142);  // row_bcast15
  DPPMAX(0x143);  // row_bcast31
#undef DPPMAX
  return __int_as_float(__builtin_amdgcn_readlane(__float_as_int(v), 63));
}

// ---------- transpose [H,C] -> [C,H] for both MLP weights ----------
__global__ __launch_bounds__(256) void transpose_w_kernel(
    const float* __restrict__ wseg, const float* __restrict__ wvote,
    float* __restrict__ tseg, float* __restrict__ tvote) {
  int i = blockIdx.x * 256 + threadIdx.x;  // 0..32767
  int c = i >> 7, o = i & 127;
  tseg[i] = wseg[o * NC + c];
  tvote[i] = wvote[o * NC + c];
}

// ---------- seg branch: 128x128 tile, 8x8 acc/thread, b128 LDS reads ----------
// Accumulation trees (k-ascending per (o,n); o-ascending 8-then-16 for S) are
// bitwise identical to the previous passing kernel - only thread mapping changed.
__global__ __launch_bounds__(256) void seg_kernel(
    const float* __restrict__ features, const float* __restrict__ w1t,
    const float* __restrict__ scale1, const float* __restrict__ bias1,
    const float* __restrict__ w2, const float* __restrict__ b2,
    float* __restrict__ seg_out, unsigned long long* __restrict__ keys) {
  __shared__ float wt[32][128];   // 16 KB
  __shared__ float ft[32][128];   // 16 KB
  __shared__ float red[16][128];  // 8 KB
  __shared__ float Ssh[128];
  __shared__ float w2sh[128];
  int b = blockIdx.y;
  int n0 = blockIdx.x * 128;
  int tid = threadIdx.x;
  int lane = tid & 63;
  int ro = tid >> 4, rc = tid & 15;
  // wave-parallel max/min of w2 (identical in every wave)
  float a0 = w2[lane], a1 = w2[lane + 64];
  float whi = fmaxf(a0, a1), wlo = fminf(a0, a1);
#pragma unroll
  for (int off = 32; off >= 1; off >>= 1) {
    whi = fmaxf(whi, __shfl_xor(whi, off, 64));
    wlo = fminf(wlo, __shfl_xor(wlo, off, 64));
  }
  if (tid < 128) w2sh[tid] = w2[tid];
  const float* fb = features + (size_t)b * NC * NP;
  float acc[8][8] = {};
  for (int kc = 0; kc < NC; kc += 32) {
    // stage wt (32x128) and ft (32x128) as float4, fully coalesced
#pragma unroll
    for (int t = 0; t < 4; ++t) {
      int q = tid + t * 256;           // 0..1023
      int kk = q >> 5, c4 = (q & 31) * 4;
      *(float4*)&wt[kk][c4] = *(const float4*)&w1t[(kc + kk) * NH + c4];
    }
#pragma unroll
    for (int t = 0; t < 4; ++t) {
      int q = tid + t * 256;
      int kk = q >> 5, c4 = (q & 31) * 4;
      *(float4*)&ft[kk][c4] = *(const float4*)&fb[(size_t)(kc + kk) * NP + n0 + c4];
    }
    __syncthreads();
#pragma unroll
    for (int kk = 0; kk < 32; ++kk) {
      float wv[8], fv[8];
#pragma unroll
      for (int i = 0; i < 8; ++i) wv[i] = wt[kk][ro * 8 + i];
#pragma unroll
      for (int j = 0; j < 8; ++j) fv[j] = ft[kk][rc * 8 + j];
#pragma unroll
      for (int i = 0; i < 8; ++i)
#pragma unroll
        for (int j = 0; j < 8; ++j) acc[i][j] = fmaf(wv[i], fv[j], acc[i][j]);
    }
    __syncthreads();
  }
  // h = relu(acc*scale+bias); partial S over this thread's 8 o's (o-ascending)
  float part[8] = {};
#pragma unroll
  for (int i = 0; i < 8; ++i) {
    int o = ro * 8 + i;
    float sc = scale1[o], bi = bias1[o];
#pragma unroll
    for (int j = 0; j < 8; ++j) {
      float h = fmaxf(fmaf(acc[i][j], sc, bi), 0.0f);
      part[j] += h;
    }
  }
#pragma unroll
  for (int j = 0; j < 8; ++j) red[ro][rc * 8 + j] = part[j];
  __syncthreads();
  float b2v = b2[0];
  if (tid < 128) {
    float S = 0.0f;
#pragma unroll
    for (int r = 0; r < 16; ++r) S += red[r][tid];  // o-ascending, same tree
    Ssh[tid] = S;
    float m = (S >= 0.0f ? whi * S : wlo * S) + b2v;
    float sig = 1.0f / (1.0f + expf(-m));
    int nn = n0 + tid;
    keys[(size_t)b * NP + nn] = make_key(sig, nn);
  }
  __syncthreads();
  // seg_out[k][n] = w2[k]*S[n]+b2 : 128x128 block, float4 stores
#pragma unroll
  for (int t = 0; t < 16; ++t) {
    int q = tid + t * 256;            // 0..4095
    int k = q >> 5, n4 = (q & 31) * 4;
    float w2k = w2sh[k];
    const float4 s4 = *(const float4*)&Ssh[n4];
    float4 sv;
    sv.x = fmaf(w2k, s4.x, b2v);
    sv.y = fmaf(w2k, s4.y, b2v);
    sv.z = fmaf(w2k, s4.z, b2v);
    sv.w = fmaf(w2k, s4.w, b2v);
    *(float4*)&seg_out[((size_t)b * 128 + k) * NP + n0 + n4] = sv;
  }
}

// ---------- bitonic sort of each 8192-key chunk (chunk0 asc, chunk1 desc) ----------
__global__ __launch_bounds__(1024) void sort8k_kernel(unsigned long long* __restrict__ keys) {
  __shared__ unsigned long long sk[8192];
  int chunk = blockIdx.x & 1, b = blockIdx.x >> 1;
  bool desc = (chunk == 1);
  unsigned long long* K = keys + (size_t)b * NP + chunk * 8192;
  int tid = threadIdx.x;
  for (int i = tid; i < 8192; i += 1024) sk[i] = K[i];
  __syncthreads();
  for (int k = 2; k <= 8192; k <<= 1) {
    for (int j = k >> 1; j > 0; j >>= 1) {
      for (int i = tid; i < 8192; i += 1024) {
        int ixj = i ^ j;
        if (ixj > i) {
          bool up = (((i & k) == 0) != desc);
          unsigned long long a = sk[i], c = sk[ixj];
          if ((a > c) == up) { sk[i] = c; sk[ixj] = a; }
        }
      }
      __syncthreads();
    }
  }
  for (int i = tid; i < 8192; i += 1024) K[i] = sk[i];
}

// ---------- bitonic merge of lower half: exact top-4096 in sorted order ----------
__global__ __launch_bounds__(1024) void merge_topk_kernel(
    const unsigned long long* __restrict__ keys, int* __restrict__ fg_idx,
    float* __restrict__ fg_xyz, const float* __restrict__ xyz) {
  __shared__ unsigned long long sk[8192];
  int b = blockIdx.x;
  const unsigned long long* K = keys + (size_t)b * NP;
  int tid = threadIdx.x;
  for (int i = tid; i < 8192; i += 1024) {
    unsigned long long a = K[i], c = K[i + 8192];
    sk[i] = (a < c) ? a : c;
  }
  __syncthreads();
  for (int j = 4096; j > 0; j >>= 1) {
    for (int i = tid; i < 8192; i += 1024) {
      int ixj = i ^ j;
      if (ixj > i) {
        unsigned long long a = sk[i], c = sk[ixj];
        if (a > c) { sk[i] = c; sk[ixj] = a; }
      }
    }
    __syncthreads();
  }
  for (int m = tid; m < NM; m += 1024) {
    unsigned long long key = sk[m];
    int idx = (int)(key & 0xffffffffULL);
    fg_idx[b * NM + m] = idx;
    size_t src = ((size_t)b * NP + idx) * 3;
    size_t dst = ((size_t)b * NM + m) * 3;
    fg_xyz[dst + 0] = xyz[src + 0];
    fg_xyz[dst + 1] = xyz[src + 1];
    fg_xyz[dst + 2] = xyz[src + 2];
  }
}

// ---------- vote branch: gathered GEMM -> vh, reg head, clip, ctr points ----------
__global__ __launch_bounds__(256) void vote_kernel(
    const float* __restrict__ features, const int* __restrict__ fg_idx,
    const float* __restrict__ w1t, const float* __restrict__ scale1,
    const float* __restrict__ bias1, const float* __restrict__ rw,
    const float* __restrict__ rb, const float* __restrict__ fg_xyz,
    float* __restrict__ vh, float* __restrict__ offs, float* __restrict__ fg_ctr) {
  __shared__ float wt[32][128];
  __shared__ float ft[32][64];
  __shared__ float hl[128][65];
  __shared__ int idx_l[64];
  int b = blockIdx.y;
  int m0 = blockIdx.x * 64;
  int tid = threadIdx.x;
  int ro = tid >> 4, rc = tid & 15;
  const float* fb = features + (size_t)b * NC * NP;
  if (tid < 64) idx_l[tid] = fg_idx[b * NM + m0 + tid];
  __syncthreads();
  float acc[8][4] = {};
  for (int kc = 0; kc < NC; kc += 32) {
    for (int q = tid; q < 4096; q += 256) {
      int kk = q >> 7, o = q & 127;
      wt[kk][o] = w1t[(kc + kk) * NH + o];
    }
    for (int q = tid; q < 2048; q += 256) {
      int kk = q >> 6, mm = q & 63;
      ft[kk][mm] = fb[(size_t)(kc + kk) * NP + idx_l[mm]];
    }
    __syncthreads();
#pragma unroll
    for (int kk = 0; kk < 32; ++kk) {
      float wv[8], fv[4];
#pragma unroll
      for (int i = 0; i < 8; ++i) wv[i] = wt[kk][ro * 8 + i];
#pragma unroll
      for (int j = 0; j < 4; ++j) fv[j] = ft[kk][rc * 4 + j];
#pragma unroll
      for (int i = 0; i < 8; ++i)
#pragma unroll
        for (int j = 0; j < 4; ++j) acc[i][j] = fmaf(wv[i], fv[j], acc[i][j]);
    }
    __syncthreads();
  }
#pragma unroll
  for (int i = 0; i < 8; ++i) {
    int o = ro * 8 + i;
    float sc = scale1[o], bi = bias1[o];
#pragma unroll
    for (int j = 0; j < 4; ++j) {
      float h = fmaxf(fmaf(acc[i][j], sc, bi), 0.0f);
      hl[o][rc * 4 + j] = h;
      vh[((size_t)b * NH + o) * NM + m0 + rc * 4 + j] = h;
    }
  }
  __syncthreads();
  if (tid < 64) {
    int m = m0 + tid;
    const float MT[3] = {3.0f, 3.0f, 2.0f};
#pragma unroll
    for (int r = 0; r < 3; ++r) {
      float a = 0.0f;
      for (int o = 0; o < NH; ++o) a = fmaf(rw[r * NH + o], hl[o][tid], a);
      a += rb[r];
      a = fminf(fmaxf(a, -MT[r]), MT[r]);
      size_t p = ((size_t)b * NM + m) * 3 + r;
      offs[p] = a;
      fg_ctr[p] = __fadd_rn(fg_xyz[p], a);
    }
  }
}

// ---------- D-FPS: R9 structure (best measured), 4 waves x 16 pts/lane ----------
#define PPT 16
__global__ __launch_bounds__(256) void fps_kernel(
    const float* __restrict__ fg_xyz, const float* __restrict__ fg_ctr,
    int* __restrict__ ori_idx, int* __restrict__ ctr_idx) {
#pragma clang fp contract(off)
  __shared__ float px[NM], py[NM], pz[NM];          // 48 KB
  __shared__ __align__(32) unsigned long long wkey[2][4];
  __shared__ int sel_list[NS];
  int set = blockIdx.x & 1, b = blockIdx.x >> 1;
  const float* P = (set == 0 ? fg_xyz : fg_ctr) + (size_t)b * NM * 3;
  int* O = (set == 0 ? ori_idx : ctr_idx) + b * NS;
  int tid = threadIdx.x;
  for (int m = tid; m < NM; m += 256) {
    px[m] = P[m * 3 + 0];
    py[m] = P[m * 3 + 1];
    pz[m] = P[m * 3 + 2];
  }
  __syncthreads();
  v2f x2[8], y2[8], z2[8], d2[8];
  int base_idx = tid * PPT;
#pragma unroll
  for (int j = 0; j < 8; ++j) {
    int m0 = base_idx + 2 * j, m1 = m0 + 1;
    v2f t;
    t.x = px[m0]; t.y = px[m1]; x2[j] = t;
    t.x = py[m0]; t.y = py[m1]; y2[j] = t;
    t.x = pz[m0]; t.y = pz[m1]; z2[j] = t;
    t.x = 3.402823466e38f; t.y = 3.402823466e38f;  // fmin(FLT_MAX,d0)==d0
    d2[j] = t;
  }
  if (tid == 0) sel_list[0] = 0;
  int lane = tid & 63, wave = tid >> 6;  // 4 waves
  float sx = px[0], sy = py[0], sz = pz[0];
  for (int it = 1; it < NS; ++it) {
    v2f sxv, syv, szv;
    sxv.x = sx; sxv.y = sx;
    syv.x = sy; syv.y = sy;
    szv.x = sz; szv.y = sz;
    // fused update (min with dist to prev selection) + local first-max, np order
    float bd = -1.0f;
    int bc = base_idx;
#pragma unroll
    for (int j = 0; j < 8; ++j) {
      v2f dx = x2[j] - sxv, dy = y2[j] - syv, dz = z2[j] - szv;
      v2f dd = (dx * dx + dy * dy) + dz * dz;  // rn, np association
      v2f nd;
      nd.x = fminf(d2[j].x, dd.x);
      nd.y = fminf(d2[j].y, dd.y);
      d2[j] = nd;
      if (j == 0) {
        bd = nd.x; bc = base_idx;
        bool g = nd.y > bd; bd = g ? nd.y : bd; bc = g ? base_idx + 1 : bc;
      } else {
        bool g0 = nd.x > bd; bd = g0 ? nd.x : bd; bc = g0 ? base_idx + 2 * j : bc;
        bool g1 = nd.y > bd; bd = g1 ? nd.y : bd; bc = g1 ? base_idx + 2 * j + 1 : bc;
      }
    }
    // wave max on VALU (DPP), exact first-index tie-break via ballot
    float wm = wave_max_dpp(bd);
    unsigned long long msk = __ballot(bd == wm);
    int wl = __ffsll((long long)msk) - 1;
    if (lane == wl)
      wkey[it & 1][wave] =
          (((unsigned long long)__float_as_uint(bd)) << 32) | (unsigned)(4095 - bc);
    __syncthreads();
    // 4-slot reduce: one 32B broadcast read + 3 u64 compares
    const ulonglong2* wk = (const ulonglong2*)&wkey[it & 1][0];
    ulonglong2 q0 = wk[0], q1 = wk[1];
    unsigned long long m0 = q0.x > q0.y ? q0.x : q0.y;
    unsigned long long m1 = q1.x > q1.y ? q1.x : q1.y;
    unsigned long long km = m0 > m1 ? m0 : m1;
    int sel = 4095 - (int)(km & 0xffffffffULL);
    if (tid == 0) sel_list[it] = sel;  // LDS, not global (vmcnt-free barrier)
    sx = px[sel]; sy = py[sel]; sz = pz[sel];  // broadcast reads
  }
  __syncthreads();
  for (int s2 = tid; s2 < NS; s2 += 256) O[s2] = sel_list[s2];
}

// ---------- agg_feat output ----------
__global__ __launch_bounds__(256) void feat_out_kernel(
    const float* __restrict__ vh, const float* __restrict__ features,
    const int* __restrict__ fg_idx, const int* __restrict__ ori_idx,
    const int* __restrict__ ctr_idx, float* __restrict__ out_feat) {
  int b = blockIdx.z;
  int o = blockIdx.y * 4 + (threadIdx.x >> 6);
  int s = blockIdx.x * 64 + (threadIdx.x & 63);
  float val;
  if (s < NS) {
    int i = ctr_idx[b * NS + s];
    val = vh[((size_t)b * NH + o) * NM + i];
  } else {
    int i = ori_idx[b * NS + (s - NS)];
    int g = fg_idx[b * NM + i];
    val = features[((size_t)b * NC + o) * NP + g];
  }
  out_feat[((size_t)b * NH + o) * (2 * NS) + s] = val;
}

// ---------- xyz / offset / origin outputs ----------
__global__ __launch_bounds__(256) void xyz_out_kernel(
    const float* __restrict__ fg_xyz, const float* __restrict__ fg_ctr,
    const float* __restrict__ offs, const int* __restrict__ ori_idx,
    const int* __restrict__ ctr_idx, float* __restrict__ out_agg,
    float* __restrict__ out_cxyz, float* __restrict__ out_coff,
    float* __restrict__ out_corg) {
  int b = blockIdx.y;
  int s = blockIdx.x * 256 + threadIdx.x;  // 0..2047
  if (s < NS) {
    int i = ctr_idx[b * NS + s];
    size_t src = ((size_t)b * NM + i) * 3;
    size_t d_agg = ((size_t)b * 2 * NS + s) * 3;
    size_t d_s = ((size_t)b * NS + s) * 3;
#pragma unroll
    for (int r = 0; r < 3; ++r) {
      float c = fg_ctr[src + r];
      out_agg[d_agg + r] = c;
      out_cxyz[d_s + r] = c;
      out_coff[d_s + r] = offs[src + r];
      out_corg[d_s + r] = fg_xyz[src + r];
    }
  } else {
    int i = ori_idx[b * NS + (s - NS)];
    size_t src = ((size_t)b * NM + i) * 3;
    size_t d_agg = ((size_t)b * 2 * NS + s) * 3;
#pragma unroll
    for (int r = 0; r < 3; ++r) out_agg[d_agg + r] = fg_xyz[src + r];
  }
}

extern "C" void kernel_launch(void* const* d_in, const int* in_sizes, int n_in,
                              void* d_out, int out_size, void* d_ws, size_t ws_size,
                              hipStream_t stream) {
  const float* xyz = (const float*)d_in[0];
  const float* features = (const float*)d_in[1];
  const float* seg_w1 = (const float*)d_in[2];
  const float* seg_scale1 = (const float*)d_in[3];
  const float* seg_bias1 = (const float*)d_in[4];
  const float* seg_w2 = (const float*)d_in[5];
  const float* seg_b2 = (const float*)d_in[6];
  const float* vote_w1 = (const float*)d_in[7];
  const float* vote_scale1 = (const float*)d_in[8];
  const float* vote_bias1 = (const float*)d_in[9];
  const float* reg_w = (const float*)d_in[10];
  const float* reg_b = (const float*)d_in[11];
  float* out = (float*)d_out;

  char* ws = (char*)d_ws;
  unsigned long long* keys = (unsigned long long*)(ws + 0);  // 1,048,576 B
  int* fg_idx = (int*)(ws + 1048576);                        // 131,072 B
  float* fg_xyz = (float*)(ws + 1179648);                    // 393,216 B
  float* fg_ctr = (float*)(ws + 1572864);                    // 393,216 B
  float* offs = (float*)(ws + 1966080);                      // 393,216 B
  int* ori_idx = (int*)(ws + 2359296);                       // 32,768 B
  int* ctr_idx = (int*)(ws + 2392064);                       // 32,768 B
  float* vh = (float*)(ws + 2424832);                        // 16,777,216 B
  float* w1t_s = (float*)(ws + 19202048);                    // 131,072 B
  float* w1t_v = (float*)(ws + 19333120);                    // 131,072 B (end 19,464,192)

  // outputs (reference return order), seg is [B,128,N]:
  float* out_agg_xyz = out;                  // [8,2048,3]      @ 0
  float* out_agg_feat = out + 49152;         // [8,128,2048]    @ 49152
  float* out_ctr_xyz = out + 2146304;        // [8,1024,3]      @ 2146304
  float* out_ctr_off = out + 2170880;        // [8,1024,3]      @ 2170880
  float* out_ctr_org = out + 2195456;        // [8,1024,3]      @ 2195456
  float* out_seg = out + 2220032;            // [8,128,16384]   @ 2220032

  transpose_w_kernel<<<128, 256, 0, stream>>>(seg_w1, vote_w1, w1t_s, w1t_v);
  seg_kernel<<<dim3(NP / 128, NB), 256, 0, stream>>>(
      features, w1t_s, seg_scale1, seg_bias1, seg_w2, seg_b2, out_seg, keys);
  sort8k_kernel<<<2 * NB, 1024, 0, stream>>>(keys);
  merge_topk_kernel<<<NB, 1024, 0, stream>>>(keys, fg_idx, fg_xyz, xyz);
  vote_kernel<<<dim3(NM / 64, NB), 256, 0, stream>>>(
      features, fg_idx, w1t_v, vote_scale1, vote_bias1, reg_w, reg_b, fg_xyz,
      vh, offs, fg_ctr);
  // one problem per block, 16 blocks in ONE dispatch (R9 structure, 4 waves)
  fps_kernel<<<16, 256, 0, stream>>>(fg_xyz, fg_ctr, ori_idx, ctr_idx);
  feat_out_kernel<<<dim3(32, 32, NB), 256, 0, stream>>>(
      vh, features, fg_idx, ori_idx, ctr_idx, out_agg_feat);
  xyz_out_kernel<<<dim3(8, NB), 256, 0, stream>>>(
      fg_xyz, fg_ctr, offs, ori_idx, ctr_idx, out_agg_xyz, out_ctr_xyz,
      out_ctr_off, out_ctr_org);
}

// Round 11
// 897.653 us; speedup vs baseline: 1.7059x; 1.0806x over previous
//
#include <hip/hip_runtime.h>

#define NB 8
#define NP 16384
#define NC 256
#define NH 128
#define NM 4096
#define NS 1024

typedef float v2f __attribute__((ext_vector_type(2)));

// ---------- helpers ----------
__device__ __forceinline__ unsigned long long make_key(float v, int n) {
  unsigned u = __float_as_uint(v);
  u = (u & 0x80000000u) ? ~u : (u | 0x80000000u);  // map float -> ascending uint
  unsigned d = ~u;                                 // descending
  return (((unsigned long long)d) << 32) | (unsigned)n;
}

__device__ __forceinline__ void ce64(unsigned long long& a, unsigned long long& c, bool up) {
  unsigned long long x = a, y = c;
  if ((x > y) == up) { a = y; c = x; }
}

// VALU-only 64-lane max (values >= 0), result broadcast via readlane(63).
__device__ __forceinline__ float wave_max_dpp(float v) {
#define DPPMAX(ctrl)                                                            \
  v = fmaxf(v, __int_as_float(__builtin_amdgcn_update_dpp(                      \
                 __float_as_int(v), __float_as_int(v), (ctrl), 0xf, 0xf, false)))
  DPPMAX(0xB1);   // quad_perm [1,0,3,2]  : xor 1
  DPPMAX(0x4E);   // quad_perm [2,3,0,1]  : xor 2
  DPPMAX(0x141);  // row_half_mirror
  DPPMAX(0x140);  // row_mirror
  DPPMAX(0x142);  // row_bcast15
  DPPMAX(0x143);  // row_bcast31
#undef DPPMAX
  return __int_as_float(__builtin_amdgcn_readlane(__float_as_int(v), 63));
}

// ---------- transpose [H,C] -> [C,H] for both MLP weights ----------
__global__ __launch_bounds__(256) void transpose_w_kernel(
    const float* __restrict__ wseg, const float* __restrict__ wvote,
    float* __restrict__ tseg, float* __restrict__ tvote) {
  int i = blockIdx.x * 256 + threadIdx.x;  // 0..32767
  int c = i >> 7, o = i & 127;
  tseg[i] = wseg[o * NC + c];
  tvote[i] = wvote[o * NC + c];
}

// ---------- seg branch: 128x128 tile, 8x8 acc/thread, b128 LDS reads ----------
__global__ __launch_bounds__(256) void seg_kernel(
    const float* __restrict__ features, const float* __restrict__ w1t,
    const float* __restrict__ scale1, const float* __restrict__ bias1,
    const float* __restrict__ w2, const float* __restrict__ b2,
    float* __restrict__ seg_out, unsigned long long* __restrict__ keys) {
  __shared__ float wt[32][128];   // 16 KB
  __shared__ float ft[32][128];   // 16 KB
  __shared__ float red[16][128];  // 8 KB
  __shared__ float Ssh[128];
  __shared__ float w2sh[128];
  int b = blockIdx.y;
  int n0 = blockIdx.x * 128;
  int tid = threadIdx.x;
  int lane = tid & 63;
  int ro = tid >> 4, rc = tid & 15;
  float a0 = w2[lane], a1 = w2[lane + 64];
  float whi = fmaxf(a0, a1), wlo = fminf(a0, a1);
#pragma unroll
  for (int off = 32; off >= 1; off >>= 1) {
    whi = fmaxf(whi, __shfl_xor(whi, off, 64));
    wlo = fminf(wlo, __shfl_xor(wlo, off, 64));
  }
  if (tid < 128) w2sh[tid] = w2[tid];
  const float* fb = features + (size_t)b * NC * NP;
  float acc[8][8] = {};
  for (int kc = 0; kc < NC; kc += 32) {
#pragma unroll
    for (int t = 0; t < 4; ++t) {
      int q = tid + t * 256;           // 0..1023
      int kk = q >> 5, c4 = (q & 31) * 4;
      *(float4*)&wt[kk][c4] = *(const float4*)&w1t[(kc + kk) * NH + c4];
    }
#pragma unroll
    for (int t = 0; t < 4; ++t) {
      int q = tid + t * 256;
      int kk = q >> 5, c4 = (q & 31) * 4;
      *(float4*)&ft[kk][c4] = *(const float4*)&fb[(size_t)(kc + kk) * NP + n0 + c4];
    }
    __syncthreads();
#pragma unroll
    for (int kk = 0; kk < 32; ++kk) {
      float wv[8], fv[8];
#pragma unroll
      for (int i = 0; i < 8; ++i) wv[i] = wt[kk][ro * 8 + i];
#pragma unroll
      for (int j = 0; j < 8; ++j) fv[j] = ft[kk][rc * 8 + j];
#pragma unroll
      for (int i = 0; i < 8; ++i)
#pragma unroll
        for (int j = 0; j < 8; ++j) acc[i][j] = fmaf(wv[i], fv[j], acc[i][j]);
    }
    __syncthreads();
  }
  float part[8] = {};
#pragma unroll
  for (int i = 0; i < 8; ++i) {
    int o = ro * 8 + i;
    float sc = scale1[o], bi = bias1[o];
#pragma unroll
    for (int j = 0; j < 8; ++j) {
      float h = fmaxf(fmaf(acc[i][j], sc, bi), 0.0f);
      part[j] += h;
    }
  }
#pragma unroll
  for (int j = 0; j < 8; ++j) red[ro][rc * 8 + j] = part[j];
  __syncthreads();
  float b2v = b2[0];
  if (tid < 128) {
    float S = 0.0f;
#pragma unroll
    for (int r = 0; r < 16; ++r) S += red[r][tid];  // o-ascending, same tree
    Ssh[tid] = S;
    float m = (S >= 0.0f ? whi * S : wlo * S) + b2v;
    float sig = 1.0f / (1.0f + expf(-m));
    int nn = n0 + tid;
    keys[(size_t)b * NP + nn] = make_key(sig, nn);
  }
  __syncthreads();
#pragma unroll
  for (int t = 0; t < 16; ++t) {
    int q = tid + t * 256;            // 0..4095
    int k = q >> 5, n4 = (q & 31) * 4;
    float w2k = w2sh[k];
    const float4 s4 = *(const float4*)&Ssh[n4];
    float4 sv;
    sv.x = fmaf(w2k, s4.x, b2v);
    sv.y = fmaf(w2k, s4.y, b2v);
    sv.z = fmaf(w2k, s4.z, b2v);
    sv.w = fmaf(w2k, s4.w, b2v);
    *(float4*)&seg_out[((size_t)b * 128 + k) * NP + n0 + n4] = sv;
  }
}

// ---------- bitonic sort of each 8192-key chunk, register-fused steps ----------
// Same comparator network as before (exact equivalence): steps j,j/2,j/4 fused
// into 8-element register groups (closed under the XORs; (i&k) group-uniform),
// tail j=4,2,1 in each thread's own contiguous 8. 91 -> 35 LDS/barrier rounds.
__global__ __launch_bounds__(1024) void sort8k_kernel(unsigned long long* __restrict__ keys) {
  __shared__ unsigned long long sk[8192];
  int chunk = blockIdx.x & 1, b = blockIdx.x >> 1;
  bool desc = (chunk == 1);
  unsigned long long* K = keys + (size_t)b * NP + chunk * 8192;
  int tid = threadIdx.x;
  for (int i = tid; i < 8192; i += 1024) sk[i] = K[i];
  __syncthreads();
  for (int k = 2; k <= 8192; k <<= 1) {
    int j = k >> 1;
    while (j >= 8) {
      if (j >= 32) {
        int ja = j, jb = j >> 1, jc = j >> 2;
        int x = tid;
        x = (x & (jc - 1)) | ((x & ~(jc - 1)) << 1);
        x = (x & (jb - 1)) | ((x & ~(jb - 1)) << 1);
        x = (x & (ja - 1)) | ((x & ~(ja - 1)) << 1);
        unsigned long long e[8];
        e[0] = sk[x];           e[1] = sk[x | jc];
        e[2] = sk[x | jb];      e[3] = sk[x | jb | jc];
        e[4] = sk[x | ja];      e[5] = sk[x | ja | jc];
        e[6] = sk[x | ja | jb]; e[7] = sk[x | ja | jb | jc];
        bool up = ((x & k) == 0) != desc;
        ce64(e[0], e[4], up); ce64(e[1], e[5], up); ce64(e[2], e[6], up); ce64(e[3], e[7], up);
        ce64(e[0], e[2], up); ce64(e[1], e[3], up); ce64(e[4], e[6], up); ce64(e[5], e[7], up);
        ce64(e[0], e[1], up); ce64(e[2], e[3], up); ce64(e[4], e[5], up); ce64(e[6], e[7], up);
        sk[x] = e[0];           sk[x | jc] = e[1];
        sk[x | jb] = e[2];      sk[x | jb | jc] = e[3];
        sk[x | ja] = e[4];      sk[x | ja | jc] = e[5];
        sk[x | ja | jb] = e[6]; sk[x | ja | jb | jc] = e[7];
        j >>= 3;
      } else if (j >= 16) {
        int ja = j, jb = j >> 1;
        for (int g = tid; g < 2048; g += 1024) {
          int x = g;
          x = (x & (jb - 1)) | ((x & ~(jb - 1)) << 1);
          x = (x & (ja - 1)) | ((x & ~(ja - 1)) << 1);
          unsigned long long e0 = sk[x], e1 = sk[x | jb];
          unsigned long long e2 = sk[x | ja], e3 = sk[x | ja | jb];
          bool up = ((x & k) == 0) != desc;
          ce64(e0, e2, up); ce64(e1, e3, up);
          ce64(e0, e1, up); ce64(e2, e3, up);
          sk[x] = e0; sk[x | jb] = e1; sk[x | ja] = e2; sk[x | ja | jb] = e3;
        }
        j >>= 2;
      } else {  // j == 8
        for (int g = tid; g < 4096; g += 1024) {
          int i = (g & 7) | ((g & ~7) << 1);
          bool up = ((i & k) == 0) != desc;
          unsigned long long a = sk[i], c = sk[i | 8];
          if ((a > c) == up) { sk[i] = c; sk[i | 8] = a; }
        }
        j >>= 1;
      }
      __syncthreads();
    }
    {  // tail: j in {4,2,1} (j < k), inside own 8 contiguous elements
      int base = tid * 8;
      unsigned long long e[8];
#pragma unroll
      for (int t = 0; t < 8; ++t) e[t] = sk[base + t];
#pragma unroll
      for (int jj = 4; jj >= 1; jj >>= 1) {
        if (jj > (k >> 1)) continue;
#pragma unroll
        for (int t = 0; t < 8; ++t)
          if (!(t & jj)) {
            bool up = (((base + t) & k) == 0) != desc;
            ce64(e[t], e[t | jj], up);
          }
      }
#pragma unroll
      for (int t = 0; t < 8; ++t) sk[base + t] = e[t];
    }
    __syncthreads();
  }
  for (int i = tid; i < 8192; i += 1024) K[i] = sk[i];
}

// ---------- bitonic merge of lower half (ascending, up=true), fused steps ----------
__global__ __launch_bounds__(1024) void merge_topk_kernel(
    const unsigned long long* __restrict__ keys, int* __restrict__ fg_idx,
    float* __restrict__ fg_xyz, const float* __restrict__ xyz) {
  __shared__ unsigned long long sk[8192];
  int b = blockIdx.x;
  const unsigned long long* K = keys + (size_t)b * NP;
  int tid = threadIdx.x;
  for (int i = tid; i < 8192; i += 1024) {
    unsigned long long a = K[i], c = K[i + 8192];
    sk[i] = (a < c) ? a : c;  // lower outputs of the k=16384, j=8192 stage
  }
  __syncthreads();
  int j = 4096;
  while (j >= 8) {
    if (j >= 32) {
      int ja = j, jb = j >> 1, jc = j >> 2;
      int x = tid;
      x = (x & (jc - 1)) | ((x & ~(jc - 1)) << 1);
      x = (x & (jb - 1)) | ((x & ~(jb - 1)) << 1);
      x = (x & (ja - 1)) | ((x & ~(ja - 1)) << 1);
      unsigned long long e[8];
      e[0] = sk[x];           e[1] = sk[x | jc];
      e[2] = sk[x | jb];      e[3] = sk[x | jb | jc];
      e[4] = sk[x | ja];      e[5] = sk[x | ja | jc];
      e[6] = sk[x | ja | jb]; e[7] = sk[x | ja | jb | jc];
      ce64(e[0], e[4], true); ce64(e[1], e[5], true); ce64(e[2], e[6], true); ce64(e[3], e[7], true);
      ce64(e[0], e[2], true); ce64(e[1], e[3], true); ce64(e[4], e[6], true); ce64(e[5], e[7], true);
      ce64(e[0], e[1], true); ce64(e[2], e[3], true); ce64(e[4], e[5], true); ce64(e[6], e[7], true);
      sk[x] = e[0];           sk[x | jc] = e[1];
      sk[x | jb] = e[2];      sk[x | jb | jc] = e[3];
      sk[x | ja] = e[4];      sk[x | ja | jc] = e[5];
      sk[x | ja | jb] = e[6]; sk[x | ja | jb | jc] = e[7];
      j >>= 3;
    } else if (j >= 16) {
      int ja = j, jb = j >> 1;
      for (int g = tid; g < 2048; g += 1024) {
        int x = g;
        x = (x & (jb - 1)) | ((x & ~(jb - 1)) << 1);
        x = (x & (ja - 1)) | ((x & ~(ja - 1)) << 1);
        unsigned long long e0 = sk[x], e1 = sk[x | jb];
        unsigned long long e2 = sk[x | ja], e3 = sk[x | ja | jb];
        ce64(e0, e2, true); ce64(e1, e3, true);
        ce64(e0, e1, true); ce64(e2, e3, true);
        sk[x] = e0; sk[x | jb] = e1; sk[x | ja] = e2; sk[x | ja | jb] = e3;
      }
      j >>= 2;
    } else {  // j == 8
      for (int g = tid; g < 4096; g += 1024) {
        int i = (g & 7) | ((g & ~7) << 1);
        unsigned long long a = sk[i], c = sk[i | 8];
        if (a > c) { sk[i] = c; sk[i | 8] = a; }
      }
      j >>= 1;
    }
    __syncthreads();
  }
  {  // tail j=4,2,1 ascending, own 8 contiguous
    int base = tid * 8;
    unsigned long long e[8];
#pragma unroll
    for (int t = 0; t < 8; ++t) e[t] = sk[base + t];
    ce64(e[0], e[4], true); ce64(e[1], e[5], true); ce64(e[2], e[6], true); ce64(e[3], e[7], true);
    ce64(e[0], e[2], true); ce64(e[1], e[3], true); ce64(e[4], e[6], true); ce64(e[5], e[7], true);
    ce64(e[0], e[1], true); ce64(e[2], e[3], true); ce64(e[4], e[5], true); ce64(e[6], e[7], true);
#pragma unroll
    for (int t = 0; t < 8; ++t) sk[base + t] = e[t];
  }
  __syncthreads();
  for (int m = tid; m < NM; m += 1024) {
    unsigned long long key = sk[m];
    int idx = (int)(key & 0xffffffffULL);
    fg_idx[b * NM + m] = idx;
    size_t src = ((size_t)b * NP + idx) * 3;
    size_t dst = ((size_t)b * NM + m) * 3;
    fg_xyz[dst + 0] = xyz[src + 0];
    fg_xyz[dst + 1] = xyz[src + 1];
    fg_xyz[dst + 2] = xyz[src + 2];
  }
}

// ---------- vote branch: gathered GEMM -> vh, reg head, clip, ctr points ----------
__global__ __launch_bounds__(256) void vote_kernel(
    const float* __restrict__ features, const int* __restrict__ fg_idx,
    const float* __restrict__ w1t, const float* __restrict__ scale1,
    const float* __restrict__ bias1, const float* __restrict__ rw,
    const float* __restrict__ rb, const float* __restrict__ fg_xyz,
    float* __restrict__ vh, float* __restrict__ offs, float* __restrict__ fg_ctr) {
  __shared__ float wt[32][128];
  __shared__ float ft[32][64];
  __shared__ float hl[128][65];
  __shared__ int idx_l[64];
  int b = blockIdx.y;
  int m0 = blockIdx.x * 64;
  int tid = threadIdx.x;
  int ro = tid >> 4, rc = tid & 15;
  const float* fb = features + (size_t)b * NC * NP;
  if (tid < 64) idx_l[tid] = fg_idx[b * NM + m0 + tid];
  __syncthreads();
  float acc[8][4] = {};
  for (int kc = 0; kc < NC; kc += 32) {
    for (int q = tid; q < 4096; q += 256) {
      int kk = q >> 7, o = q & 127;
      wt[kk][o] = w1t[(kc + kk) * NH + o];
    }
    for (int q = tid; q < 2048; q += 256) {
      int kk = q >> 6, mm = q & 63;
      ft[kk][mm] = fb[(size_t)(kc + kk) * NP + idx_l[mm]];
    }
    __syncthreads();
#pragma unroll
    for (int kk = 0; kk < 32; ++kk) {
      float wv[8], fv[4];
#pragma unroll
      for (int i = 0; i < 8; ++i) wv[i] = wt[kk][ro * 8 + i];
#pragma unroll
      for (int j = 0; j < 4; ++j) fv[j] = ft[kk][rc * 4 + j];
#pragma unroll
      for (int i = 0; i < 8; ++i)
#pragma unroll
        for (int j = 0; j < 4; ++j) acc[i][j] = fmaf(wv[i], fv[j], acc[i][j]);
    }
    __syncthreads();
  }
#pragma unroll
  for (int i = 0; i < 8; ++i) {
    int o = ro * 8 + i;
    float sc = scale1[o], bi = bias1[o];
#pragma unroll
    for (int j = 0; j < 4; ++j) {
      float h = fmaxf(fmaf(acc[i][j], sc, bi), 0.0f);
      hl[o][rc * 4 + j] = h;
      vh[((size_t)b * NH + o) * NM + m0 + rc * 4 + j] = h;
    }
  }
  __syncthreads();
  if (tid < 64) {
    int m = m0 + tid;
    const float MT[3] = {3.0f, 3.0f, 2.0f};
#pragma unroll
    for (int r = 0; r < 3; ++r) {
      float a = 0.0f;
      for (int o = 0; o < NH; ++o) a = fmaf(rw[r * NH + o], hl[o][tid], a);
      a += rb[r];
      a = fminf(fmaxf(a, -MT[r]), MT[r]);
      size_t p = ((size_t)b * NM + m) * 3 + r;
      offs[p] = a;
      fg_ctr[p] = __fadd_rn(fg_xyz[p], a);
    }
  }
}

// ---------- D-FPS: R9 structure (best measured), 4 waves x 16 pts/lane ----------
#define PPT 16
__global__ __launch_bounds__(256) void fps_kernel(
    const float* __restrict__ fg_xyz, const float* __restrict__ fg_ctr,
    int* __restrict__ ori_idx, int* __restrict__ ctr_idx) {
#pragma clang fp contract(off)
  __shared__ float px[NM], py[NM], pz[NM];          // 48 KB
  __shared__ __align__(32) unsigned long long wkey[2][4];
  __shared__ int sel_list[NS];
  int set = blockIdx.x & 1, b = blockIdx.x >> 1;
  const float* P = (set == 0 ? fg_xyz : fg_ctr) + (size_t)b * NM * 3;
  int* O = (set == 0 ? ori_idx : ctr_idx) + b * NS;
  int tid = threadIdx.x;
  for (int m = tid; m < NM; m += 256) {
    px[m] = P[m * 3 + 0];
    py[m] = P[m * 3 + 1];
    pz[m] = P[m * 3 + 2];
  }
  __syncthreads();
  v2f x2[8], y2[8], z2[8], d2[8];
  int base_idx = tid * PPT;
#pragma unroll
  for (int j = 0; j < 8; ++j) {
    int m0 = base_idx + 2 * j, m1 = m0 + 1;
    v2f t;
    t.x = px[m0]; t.y = px[m1]; x2[j] = t;
    t.x = py[m0]; t.y = py[m1]; y2[j] = t;
    t.x = pz[m0]; t.y = pz[m1]; z2[j] = t;
    t.x = 3.402823466e38f; t.y = 3.402823466e38f;  // fmin(FLT_MAX,d0)==d0
    d2[j] = t;
  }
  if (tid == 0) sel_list[0] = 0;
  int lane = tid & 63, wave = tid >> 6;  // 4 waves
  float sx = px[0], sy = py[0], sz = pz[0];
  for (int it = 1; it < NS; ++it) {
    v2f sxv, syv, szv;
    sxv.x = sx; sxv.y = sx;
    syv.x = sy; syv.y = sy;
    szv.x = sz; szv.y = sz;
    float bd = -1.0f;
    int bc = base_idx;
#pragma unroll
    for (int j = 0; j < 8; ++j) {
      v2f dx = x2[j] - sxv, dy = y2[j] - syv, dz = z2[j] - szv;
      v2f dd = (dx * dx + dy * dy) + dz * dz;  // rn, np association
      v2f nd;
      nd.x = fminf(d2[j].x, dd.x);
      nd.y = fminf(d2[j].y, dd.y);
      d2[j] = nd;
      if (j == 0) {
        bd = nd.x; bc = base_idx;
        bool g = nd.y > bd; bd = g ? nd.y : bd; bc = g ? base_idx + 1 : bc;
      } else {
        bool g0 = nd.x > bd; bd = g0 ? nd.x : bd; bc = g0 ? base_idx + 2 * j : bc;
        bool g1 = nd.y > bd; bd = g1 ? nd.y : bd; bc = g1 ? base_idx + 2 * j + 1 : bc;
      }
    }
    float wm = wave_max_dpp(bd);
    unsigned long long msk = __ballot(bd == wm);
    int wl = __ffsll((long long)msk) - 1;
    if (lane == wl)
      wkey[it & 1][wave] =
          (((unsigned long long)__float_as_uint(bd)) << 32) | (unsigned)(4095 - bc);
    __syncthreads();
    const ulonglong2* wk = (const ulonglong2*)&wkey[it & 1][0];
    ulonglong2 q0 = wk[0], q1 = wk[1];
    unsigned long long m0 = q0.x > q0.y ? q0.x : q0.y;
    unsigned long long m1 = q1.x > q1.y ? q1.x : q1.y;
    unsigned long long km = m0 > m1 ? m0 : m1;
    int sel = 4095 - (int)(km & 0xffffffffULL);
    if (tid == 0) sel_list[it] = sel;  // LDS, not global (vmcnt-free barrier)
    sx = px[sel]; sy = py[sel]; sz = pz[sel];  // broadcast reads
  }
  __syncthreads();
  for (int s2 = tid; s2 < NS; s2 += 256) O[s2] = sel_list[s2];
}

// ---------- agg_feat output ----------
__global__ __launch_bounds__(256) void feat_out_kernel(
    const float* __restrict__ vh, const float* __restrict__ features,
    const int* __restrict__ fg_idx, const int* __restrict__ ori_idx,
    const int* __restrict__ ctr_idx, float* __restrict__ out_feat) {
  int b = blockIdx.z;
  int o = blockIdx.y * 4 + (threadIdx.x >> 6);
  int s = blockIdx.x * 64 + (threadIdx.x & 63);
  float val;
  if (s < NS) {
    int i = ctr_idx[b * NS + s];
    val = vh[((size_t)b * NH + o) * NM + i];
  } else {
    int i = ori_idx[b * NS + (s - NS)];
    int g = fg_idx[b * NM + i];
    val = features[((size_t)b * NC + o) * NP + g];
  }
  out_feat[((size_t)b * NH + o) * (2 * NS) + s] = val;
}

// ---------- xyz / offset / origin outputs ----------
__global__ __launch_bounds__(256) void xyz_out_kernel(
    const float* __restrict__ fg_xyz, const float* __restrict__ fg_ctr,
    const float* __restrict__ offs, const int* __restrict__ ori_idx,
    const int* __restrict__ ctr_idx, float* __restrict__ out_agg,
    float* __restrict__ out_cxyz, float* __restrict__ out_coff,
    float* __restrict__ out_corg) {
  int b = blockIdx.y;
  int s = blockIdx.x * 256 + threadIdx.x;  // 0..2047
  if (s < NS) {
    int i = ctr_idx[b * NS + s];
    size_t src = ((size_t)b * NM + i) * 3;
    size_t d_agg = ((size_t)b * 2 * NS + s) * 3;
    size_t d_s = ((size_t)b * NS + s) * 3;
#pragma unroll
    for (int r = 0; r < 3; ++r) {
      float c = fg_ctr[src + r];
      out_agg[d_agg + r] = c;
      out_cxyz[d_s + r] = c;
      out_coff[d_s + r] = offs[src + r];
      out_corg[d_s + r] = fg_xyz[src + r];
    }
  } else {
    int i = ori_idx[b * NS + (s - NS)];
    size_t src = ((size_t)b * NM + i) * 3;
    size_t d_agg = ((size_t)b * 2 * NS + s) * 3;
#pragma unroll
    for (int r = 0; r < 3; ++r) out_agg[d_agg + r] = fg_xyz[src + r];
  }
}

extern "C" void kernel_launch(void* const* d_in, const int* in_sizes, int n_in,
                              void* d_out, int out_size, void* d_ws, size_t ws_size,
                              hipStream_t stream) {
  const float* xyz = (const float*)d_in[0];
  const float* features = (const float*)d_in[1];
  const float* seg_w1 = (const float*)d_in[2];
  const float* seg_scale1 = (const float*)d_in[3];
  const float* seg_bias1 = (const float*)d_in[4];
  const float* seg_w2 = (const float*)d_in[5];
  const float* seg_b2 = (const float*)d_in[6];
  const float* vote_w1 = (const float*)d_in[7];
  const float* vote_scale1 = (const float*)d_in[8];
  const float* vote_bias1 = (const float*)d_in[9];
  const float* reg_w = (const float*)d_in[10];
  const float* reg_b = (const float*)d_in[11];
  float* out = (float*)d_out;

  char* ws = (char*)d_ws;
  unsigned long long* keys = (unsigned long long*)(ws + 0);  // 1,048,576 B
  int* fg_idx = (int*)(ws + 1048576);                        // 131,072 B
  float* fg_xyz = (float*)(ws + 1179648);                    // 393,216 B
  float* fg_ctr = (float*)(ws + 1572864);                    // 393,216 B
  float* offs = (float*)(ws + 1966080);                      // 393,216 B
  int* ori_idx = (int*)(ws + 2359296);                       // 32,768 B
  int* ctr_idx = (int*)(ws + 2392064);                       // 32,768 B
  float* vh = (float*)(ws + 2424832);                        // 16,777,216 B
  float* w1t_s = (float*)(ws + 19202048);                    // 131,072 B
  float* w1t_v = (float*)(ws + 19333120);                    // 131,072 B (end 19,464,192)

  // outputs (reference return order), seg is [B,128,N]:
  float* out_agg_xyz = out;                  // [8,2048,3]      @ 0
  float* out_agg_feat = out + 49152;         // [8,128,2048]    @ 49152
  float* out_ctr_xyz = out + 2146304;        // [8,1024,3]      @ 2146304
  float* out_ctr_off = out + 2170880;        // [8,1024,3]      @ 2170880
  float* out_ctr_org = out + 2195456;        // [8,1024,3]      @ 2195456
  float* out_seg = out + 2220032;            // [8,128,16384]   @ 2220032

  transpose_w_kernel<<<128, 256, 0, stream>>>(seg_w1, vote_w1, w1t_s, w1t_v);
  seg_kernel<<<dim3(NP / 128, NB), 256, 0, stream>>>(
      features, w1t_s, seg_scale1, seg_bias1, seg_w2, seg_b2, out_seg, keys);
  sort8k_kernel<<<2 * NB, 1024, 0, stream>>>(keys);
  merge_topk_kernel<<<NB, 1024, 0, stream>>>(keys, fg_idx, fg_xyz, xyz);
  vote_kernel<<<dim3(NM / 64, NB), 256, 0, stream>>>(
      features, fg_idx, w1t_v, vote_scale1, vote_bias1, reg_w, reg_b, fg_xyz,
      vh, offs, fg_ctr);
  fps_kernel<<<16, 256, 0, stream>>>(fg_xyz, fg_ctr, ori_idx, ctr_idx);
  feat_out_kernel<<<dim3(32, 32, NB), 256, 0, stream>>>(
      vh, features, fg_idx, ori_idx, ctr_idx, out_agg_feat);
  xyz_out_kernel<<<dim3(8, NB), 256, 0, stream>>>(
      fg_xyz, fg_ctr, offs, ori_idx, ctr_idx, out_agg_xyz, out_ctr_xyz,
      out_ctr_off, out_ctr_org);
}

// Round 12
// 897.100 us; speedup vs baseline: 1.7070x; 1.0006x over previous
//
#include <hip/hip_runtime.h>

#define NB 8
#define NP 16384
#define NC 256
#define NH 128
#define NM 4096
#define NS 1024

typedef float v2f __attribute__((ext_vector_type(2)));

// ---------- helpers ----------
__device__ __forceinline__ unsigned long long make_key(float v, int n) {
  unsigned u = __float_as_uint(v);
  u = (u & 0x80000000u) ? ~u : (u | 0x80000000u);  // map float -> ascending uint
  unsigned d = ~u;                                 // descending
  return (((unsigned long long)d) << 32) | (unsigned)n;
}

__device__ __forceinline__ void ce64(unsigned long long& a, unsigned long long& c, bool up) {
  unsigned long long x = a, y = c;
  if ((x > y) == up) { a = y; c = x; }
}

// VALU-only 64-lane max (values >= 0), result broadcast via readlane(63).
__device__ __forceinline__ float wave_max_dpp(float v) {
#define DPPMAX(ctrl)                                                            \
  v = fmaxf(v, __int_as_float(__builtin_amdgcn_update_dpp(                      \
                 __float_as_int(v), __float_as_int(v), (ctrl), 0xf, 0xf, false)))
  DPPMAX(0xB1);   // quad_perm [1,0,3,2]  : xor 1
  DPPMAX(0x4E);   // quad_perm [2,3,0,1]  : xor 2
  DPPMAX(0x141);  // row_half_mirror
  DPPMAX(0x140);  // row_mirror
  DPPMAX(0x142);  // row_bcast15
  DPPMAX(0x143);  // row_bcast31
#undef DPPMAX
  return __int_as_float(__builtin_amdgcn_readlane(__float_as_int(v), 63));
}

// ---------- seg branch: 128x128 tile, 8x8 acc/thread, b128 LDS reads ----------
// Weights staged directly from row-major w1 [o][c]; values entering wt[kk][o]
// are bit-identical to the old transpose+load path.
__global__ __launch_bounds__(256) void seg_kernel(
    const float* __restrict__ w1, const float* __restrict__ features,
    const float* __restrict__ scale1, const float* __restrict__ bias1,
    const float* __restrict__ w2, const float* __restrict__ b2,
    float* __restrict__ seg_out, unsigned long long* __restrict__ keys) {
  __shared__ float wt[32][128];   // 16 KB
  __shared__ float ft[32][128];   // 16 KB
  __shared__ float red[16][128];  // 8 KB
  __shared__ float Ssh[128];
  __shared__ float w2sh[128];
  int b = blockIdx.y;
  int n0 = blockIdx.x * 128;
  int tid = threadIdx.x;
  int lane = tid & 63;
  int ro = tid >> 4, rc = tid & 15;
  float a0 = w2[lane], a1 = w2[lane + 64];
  float whi = fmaxf(a0, a1), wlo = fminf(a0, a1);
#pragma unroll
  for (int off = 32; off >= 1; off >>= 1) {
    whi = fmaxf(whi, __shfl_xor(whi, off, 64));
    wlo = fminf(wlo, __shfl_xor(wlo, off, 64));
  }
  if (tid < 128) w2sh[tid] = w2[tid];
  const float* fb = features + (size_t)b * NC * NP;
  float acc[8][8] = {};
  for (int kc = 0; kc < NC; kc += 32) {
    // stage wt[kk][o] from w1[o][kc+kk]: float4 along c, scatter LDS stores
#pragma unroll
    for (int t = 0; t < 4; ++t) {
      int q = tid + t * 256;          // 0..1023
      int o = q >> 3, c4 = (q & 7) * 4;
      float4 v = *(const float4*)&w1[o * NC + kc + c4];
      wt[c4 + 0][o] = v.x;
      wt[c4 + 1][o] = v.y;
      wt[c4 + 2][o] = v.z;
      wt[c4 + 3][o] = v.w;
    }
#pragma unroll
    for (int t = 0; t < 4; ++t) {
      int q = tid + t * 256;
      int kk = q >> 5, c4 = (q & 31) * 4;
      *(float4*)&ft[kk][c4] = *(const float4*)&fb[(size_t)(kc + kk) * NP + n0 + c4];
    }
    __syncthreads();
#pragma unroll
    for (int kk = 0; kk < 32; ++kk) {
      float wv[8], fv[8];
#pragma unroll
      for (int i = 0; i < 8; ++i) wv[i] = wt[kk][ro * 8 + i];
#pragma unroll
      for (int j = 0; j < 8; ++j) fv[j] = ft[kk][rc * 8 + j];
#pragma unroll
      for (int i = 0; i < 8; ++i)
#pragma unroll
        for (int j = 0; j < 8; ++j) acc[i][j] = fmaf(wv[i], fv[j], acc[i][j]);
    }
    __syncthreads();
  }
  float part[8] = {};
#pragma unroll
  for (int i = 0; i < 8; ++i) {
    int o = ro * 8 + i;
    float sc = scale1[o], bi = bias1[o];
#pragma unroll
    for (int j = 0; j < 8; ++j) {
      float h = fmaxf(fmaf(acc[i][j], sc, bi), 0.0f);
      part[j] += h;
    }
  }
#pragma unroll
  for (int j = 0; j < 8; ++j) red[ro][rc * 8 + j] = part[j];
  __syncthreads();
  float b2v = b2[0];
  if (tid < 128) {
    float S = 0.0f;
#pragma unroll
    for (int r = 0; r < 16; ++r) S += red[r][tid];  // o-ascending, same tree
    Ssh[tid] = S;
    float m = (S >= 0.0f ? whi * S : wlo * S) + b2v;
    float sig = 1.0f / (1.0f + expf(-m));
    int nn = n0 + tid;
    keys[(size_t)b * NP + nn] = make_key(sig, nn);
  }
  __syncthreads();
#pragma unroll
  for (int t = 0; t < 16; ++t) {
    int q = tid + t * 256;            // 0..4095
    int k = q >> 5, n4 = (q & 31) * 4;
    float w2k = w2sh[k];
    const float4 s4 = *(const float4*)&Ssh[n4];
    float4 sv;
    sv.x = fmaf(w2k, s4.x, b2v);
    sv.y = fmaf(w2k, s4.y, b2v);
    sv.z = fmaf(w2k, s4.z, b2v);
    sv.w = fmaf(w2k, s4.w, b2v);
    *(float4*)&seg_out[((size_t)b * 128 + k) * NP + n0 + n4] = sv;
  }
}

// ---------- bitonic sort of each 8192-key chunk, register-fused steps ----------
__global__ __launch_bounds__(1024) void sort8k_kernel(unsigned long long* __restrict__ keys) {
  __shared__ unsigned long long sk[8192];
  int chunk = blockIdx.x & 1, b = blockIdx.x >> 1;
  bool desc = (chunk == 1);
  unsigned long long* K = keys + (size_t)b * NP + chunk * 8192;
  int tid = threadIdx.x;
  for (int i = tid; i < 8192; i += 1024) sk[i] = K[i];
  __syncthreads();
  for (int k = 2; k <= 8192; k <<= 1) {
    int j = k >> 1;
    while (j >= 8) {
      if (j >= 32) {
        int ja = j, jb = j >> 1, jc = j >> 2;
        int x = tid;
        x = (x & (jc - 1)) | ((x & ~(jc - 1)) << 1);
        x = (x & (jb - 1)) | ((x & ~(jb - 1)) << 1);
        x = (x & (ja - 1)) | ((x & ~(ja - 1)) << 1);
        unsigned long long e[8];
        e[0] = sk[x];           e[1] = sk[x | jc];
        e[2] = sk[x | jb];      e[3] = sk[x | jb | jc];
        e[4] = sk[x | ja];      e[5] = sk[x | ja | jc];
        e[6] = sk[x | ja | jb]; e[7] = sk[x | ja | jb | jc];
        bool up = ((x & k) == 0) != desc;
        ce64(e[0], e[4], up); ce64(e[1], e[5], up); ce64(e[2], e[6], up); ce64(e[3], e[7], up);
        ce64(e[0], e[2], up); ce64(e[1], e[3], up); ce64(e[4], e[6], up); ce64(e[5], e[7], up);
        ce64(e[0], e[1], up); ce64(e[2], e[3], up); ce64(e[4], e[5], up); ce64(e[6], e[7], up);
        sk[x] = e[0];           sk[x | jc] = e[1];
        sk[x | jb] = e[2];      sk[x | jb | jc] = e[3];
        sk[x | ja] = e[4];      sk[x | ja | jc] = e[5];
        sk[x | ja | jb] = e[6]; sk[x | ja | jb | jc] = e[7];
        j >>= 3;
      } else if (j >= 16) {
        int ja = j, jb = j >> 1;
        for (int g = tid; g < 2048; g += 1024) {
          int x = g;
          x = (x & (jb - 1)) | ((x & ~(jb - 1)) << 1);
          x = (x & (ja - 1)) | ((x & ~(ja - 1)) << 1);
          unsigned long long e0 = sk[x], e1 = sk[x | jb];
          unsigned long long e2 = sk[x | ja], e3 = sk[x | ja | jb];
          bool up = ((x & k) == 0) != desc;
          ce64(e0, e2, up); ce64(e1, e3, up);
          ce64(e0, e1, up); ce64(e2, e3, up);
          sk[x] = e0; sk[x | jb] = e1; sk[x | ja] = e2; sk[x | ja | jb] = e3;
        }
        j >>= 2;
      } else {  // j == 8
        for (int g = tid; g < 4096; g += 1024) {
          int i = (g & 7) | ((g & ~7) << 1);
          bool up = ((i & k) == 0) != desc;
          unsigned long long a = sk[i], c = sk[i | 8];
          if ((a > c) == up) { sk[i] = c; sk[i | 8] = a; }
        }
        j >>= 1;
      }
      __syncthreads();
    }
    {  // tail: j in {4,2,1} (j < k), inside own 8 contiguous elements
      int base = tid * 8;
      unsigned long long e[8];
#pragma unroll
      for (int t = 0; t < 8; ++t) e[t] = sk[base + t];
#pragma unroll
      for (int jj = 4; jj >= 1; jj >>= 1) {
        if (jj > (k >> 1)) continue;
#pragma unroll
        for (int t = 0; t < 8; ++t)
          if (!(t & jj)) {
            bool up = (((base + t) & k) == 0) != desc;
            ce64(e[t], e[t | jj], up);
          }
      }
#pragma unroll
      for (int t = 0; t < 8; ++t) sk[base + t] = e[t];
    }
    __syncthreads();
  }
  for (int i = tid; i < 8192; i += 1024) K[i] = sk[i];
}

// ---------- bitonic merge of lower half (ascending), fused steps ----------
__global__ __launch_bounds__(1024) void merge_topk_kernel(
    const unsigned long long* __restrict__ keys, int* __restrict__ fg_idx,
    float* __restrict__ fg_xyz, const float* __restrict__ xyz) {
  __shared__ unsigned long long sk[8192];
  int b = blockIdx.x;
  const unsigned long long* K = keys + (size_t)b * NP;
  int tid = threadIdx.x;
  for (int i = tid; i < 8192; i += 1024) {
    unsigned long long a = K[i], c = K[i + 8192];
    sk[i] = (a < c) ? a : c;
  }
  __syncthreads();
  int j = 4096;
  while (j >= 8) {
    if (j >= 32) {
      int ja = j, jb = j >> 1, jc = j >> 2;
      int x = tid;
      x = (x & (jc - 1)) | ((x & ~(jc - 1)) << 1);
      x = (x & (jb - 1)) | ((x & ~(jb - 1)) << 1);
      x = (x & (ja - 1)) | ((x & ~(ja - 1)) << 1);
      unsigned long long e[8];
      e[0] = sk[x];           e[1] = sk[x | jc];
      e[2] = sk[x | jb];      e[3] = sk[x | jb | jc];
      e[4] = sk[x | ja];      e[5] = sk[x | ja | jc];
      e[6] = sk[x | ja | jb]; e[7] = sk[x | ja | jb | jc];
      ce64(e[0], e[4], true); ce64(e[1], e[5], true); ce64(e[2], e[6], true); ce64(e[3], e[7], true);
      ce64(e[0], e[2], true); ce64(e[1], e[3], true); ce64(e[4], e[6], true); ce64(e[5], e[7], true);
      ce64(e[0], e[1], true); ce64(e[2], e[3], true); ce64(e[4], e[5], true); ce64(e[6], e[7], true);
      sk[x] = e[0];           sk[x | jc] = e[1];
      sk[x | jb] = e[2];      sk[x | jb | jc] = e[3];
      sk[x | ja] = e[4];      sk[x | ja | jc] = e[5];
      sk[x | ja | jb] = e[6]; sk[x | ja | jb | jc] = e[7];
      j >>= 3;
    } else if (j >= 16) {
      int ja = j, jb = j >> 1;
      for (int g = tid; g < 2048; g += 1024) {
        int x = g;
        x = (x & (jb - 1)) | ((x & ~(jb - 1)) << 1);
        x = (x & (ja - 1)) | ((x & ~(ja - 1)) << 1);
        unsigned long long e0 = sk[x], e1 = sk[x | jb];
        unsigned long long e2 = sk[x | ja], e3 = sk[x | ja | jb];
        ce64(e0, e2, true); ce64(e1, e3, true);
        ce64(e0, e1, true); ce64(e2, e3, true);
        sk[x] = e0; sk[x | jb] = e1; sk[x | ja] = e2; sk[x | ja | jb] = e3;
      }
      j >>= 2;
    } else {  // j == 8
      for (int g = tid; g < 4096; g += 1024) {
        int i = (g & 7) | ((g & ~7) << 1);
        unsigned long long a = sk[i], c = sk[i | 8];
        if (a > c) { sk[i] = c; sk[i | 8] = a; }
      }
      j >>= 1;
    }
    __syncthreads();
  }
  {  // tail j=4,2,1 ascending, own 8 contiguous
    int base = tid * 8;
    unsigned long long e[8];
#pragma unroll
    for (int t = 0; t < 8; ++t) e[t] = sk[base + t];
    ce64(e[0], e[4], true); ce64(e[1], e[5], true); ce64(e[2], e[6], true); ce64(e[3], e[7], true);
    ce64(e[0], e[2], true); ce64(e[1], e[3], true); ce64(e[4], e[6], true); ce64(e[5], e[7], true);
    ce64(e[0], e[1], true); ce64(e[2], e[3], true); ce64(e[4], e[5], true); ce64(e[6], e[7], true);
#pragma unroll
    for (int t = 0; t < 8; ++t) sk[base + t] = e[t];
  }
  __syncthreads();
  for (int m = tid; m < NM; m += 1024) {
    unsigned long long key = sk[m];
    int idx = (int)(key & 0xffffffffULL);
    fg_idx[b * NM + m] = idx;
    size_t src = ((size_t)b * NP + idx) * 3;
    size_t dst = ((size_t)b * NM + m) * 3;
    fg_xyz[dst + 0] = xyz[src + 0];
    fg_xyz[dst + 1] = xyz[src + 1];
    fg_xyz[dst + 2] = xyz[src + 2];
  }
}

// ---------- vote branch: gathered GEMM -> vh, reg head, clip, ctr points ----------
__global__ __launch_bounds__(256) void vote_kernel(
    const float* __restrict__ features, const int* __restrict__ fg_idx,
    const float* __restrict__ w1, const float* __restrict__ scale1,
    const float* __restrict__ bias1, const float* __restrict__ rw,
    const float* __restrict__ rb, const float* __restrict__ fg_xyz,
    float* __restrict__ vh, float* __restrict__ offs, float* __restrict__ fg_ctr) {
  __shared__ float wt[32][128];
  __shared__ float ft[32][64];
  __shared__ float hl[128][65];
  __shared__ int idx_l[64];
  int b = blockIdx.y;
  int m0 = blockIdx.x * 64;
  int tid = threadIdx.x;
  int ro = tid >> 4, rc = tid & 15;
  const float* fb = features + (size_t)b * NC * NP;
  if (tid < 64) idx_l[tid] = fg_idx[b * NM + m0 + tid];
  __syncthreads();
  float acc[8][4] = {};
  for (int kc = 0; kc < NC; kc += 32) {
#pragma unroll
    for (int t = 0; t < 4; ++t) {
      int q = tid + t * 256;          // 0..1023
      int o = q >> 3, c4 = (q & 7) * 4;
      float4 v = *(const float4*)&w1[o * NC + kc + c4];
      wt[c4 + 0][o] = v.x;
      wt[c4 + 1][o] = v.y;
      wt[c4 + 2][o] = v.z;
      wt[c4 + 3][o] = v.w;
    }
    for (int q = tid; q < 2048; q += 256) {
      int kk = q >> 6, mm = q & 63;
      ft[kk][mm] = fb[(size_t)(kc + kk) * NP + idx_l[mm]];
    }
    __syncthreads();
#pragma unroll
    for (int kk = 0; kk < 32; ++kk) {
      float wv[8], fv[4];
#pragma unroll
      for (int i = 0; i < 8; ++i) wv[i] = wt[kk][ro * 8 + i];
#pragma unroll
      for (int j = 0; j < 4; ++j) fv[j] = ft[kk][rc * 4 + j];
#pragma unroll
      for (int i = 0; i < 8; ++i)
#pragma unroll
        for (int j = 0; j < 4; ++j) acc[i][j] = fmaf(wv[i], fv[j], acc[i][j]);
    }
    __syncthreads();
  }
#pragma unroll
  for (int i = 0; i < 8; ++i) {
    int o = ro * 8 + i;
    float sc = scale1[o], bi = bias1[o];
#pragma unroll
    for (int j = 0; j < 4; ++j) {
      float h = fmaxf(fmaf(acc[i][j], sc, bi), 0.0f);
      hl[o][rc * 4 + j] = h;
      vh[((size_t)b * NH + o) * NM + m0 + rc * 4 + j] = h;
    }
  }
  __syncthreads();
  if (tid < 64) {
    int m = m0 + tid;
    const float MT[3] = {3.0f, 3.0f, 2.0f};
#pragma unroll
    for (int r = 0; r < 3; ++r) {
      float a = 0.0f;
      for (int o = 0; o < NH; ++o) a = fmaf(rw[r * NH + o], hl[o][tid], a);
      a += rb[r];
      a = fminf(fmaxf(a, -MT[r]), MT[r]);
      size_t p = ((size_t)b * NM + m) * 3 + r;
      offs[p] = a;
      fg_ctr[p] = __fadd_rn(fg_xyz[p], a);
    }
  }
}

// ---------- D-FPS: frozen R9 structure, 4 waves x 16 pts/lane ----------
#define PPT 16
__global__ __launch_bounds__(256) void fps_kernel(
    const float* __restrict__ fg_xyz, const float* __restrict__ fg_ctr,
    int* __restrict__ ori_idx, int* __restrict__ ctr_idx) {
#pragma clang fp contract(off)
  __shared__ float px[NM], py[NM], pz[NM];          // 48 KB
  __shared__ __align__(32) unsigned long long wkey[2][4];
  __shared__ int sel_list[NS];
  int set = blockIdx.x & 1, b = blockIdx.x >> 1;
  const float* P = (set == 0 ? fg_xyz : fg_ctr) + (size_t)b * NM * 3;
  int* O = (set == 0 ? ori_idx : ctr_idx) + b * NS;
  int tid = threadIdx.x;
  for (int m = tid; m < NM; m += 256) {
    px[m] = P[m * 3 + 0];
    py[m] = P[m * 3 + 1];
    pz[m] = P[m * 3 + 2];
  }
  __syncthreads();
  v2f x2[8], y2[8], z2[8], d2[8];
  int base_idx = tid * PPT;
#pragma unroll
  for (int j = 0; j < 8; ++j) {
    int m0 = base_idx + 2 * j, m1 = m0 + 1;
    v2f t;
    t.x = px[m0]; t.y = px[m1]; x2[j] = t;
    t.x = py[m0]; t.y = py[m1]; y2[j] = t;
    t.x = pz[m0]; t.y = pz[m1]; z2[j] = t;
    t.x = 3.402823466e38f; t.y = 3.402823466e38f;  // fmin(FLT_MAX,d0)==d0
    d2[j] = t;
  }
  if (tid == 0) sel_list[0] = 0;
  int lane = tid & 63, wave = tid >> 6;  // 4 waves
  float sx = px[0], sy = py[0], sz = pz[0];
  for (int it = 1; it < NS; ++it) {
    v2f sxv, syv, szv;
    sxv.x = sx; sxv.y = sx;
    syv.x = sy; syv.y = sy;
    szv.x = sz; szv.y = sz;
    float bd = -1.0f;
    int bc = base_idx;
#pragma unroll
    for (int j = 0; j < 8; ++j) {
      v2f dx = x2[j] - sxv, dy = y2[j] - syv, dz = z2[j] - szv;
      v2f dd = (dx * dx + dy * dy) + dz * dz;  // rn, np association
      v2f nd;
      nd.x = fminf(d2[j].x, dd.x);
      nd.y = fminf(d2[j].y, dd.y);
      d2[j] = nd;
      if (j == 0) {
        bd = nd.x; bc = base_idx;
        bool g = nd.y > bd; bd = g ? nd.y : bd; bc = g ? base_idx + 1 : bc;
      } else {
        bool g0 = nd.x > bd; bd = g0 ? nd.x : bd; bc = g0 ? base_idx + 2 * j : bc;
        bool g1 = nd.y > bd; bd = g1 ? nd.y : bd; bc = g1 ? base_idx + 2 * j + 1 : bc;
      }
    }
    float wm = wave_max_dpp(bd);
    unsigned long long msk = __ballot(bd == wm);
    int wl = __ffsll((long long)msk) - 1;
    if (lane == wl)
      wkey[it & 1][wave] =
          (((unsigned long long)__float_as_uint(bd)) << 32) | (unsigned)(4095 - bc);
    __syncthreads();
    const ulonglong2* wk = (const ulonglong2*)&wkey[it & 1][0];
    ulonglong2 q0 = wk[0], q1 = wk[1];
    unsigned long long m0 = q0.x > q0.y ? q0.x : q0.y;
    unsigned long long m1 = q1.x > q1.y ? q1.x : q1.y;
    unsigned long long km = m0 > m1 ? m0 : m1;
    int sel = 4095 - (int)(km & 0xffffffffULL);
    if (tid == 0) sel_list[it] = sel;  // LDS, not global (vmcnt-free barrier)
    sx = px[sel]; sy = py[sel]; sz = pz[sel];  // broadcast reads
  }
  __syncthreads();
  for (int s2 = tid; s2 < NS; s2 += 256) O[s2] = sel_list[s2];
}

// ---------- fused outputs: agg_feat (y<32) + xyz/offset/origin (y==32) ----------
__global__ __launch_bounds__(256) void out_kernel(
    const float* __restrict__ vh, const float* __restrict__ features,
    const int* __restrict__ fg_idx, const int* __restrict__ ori_idx,
    const int* __restrict__ ctr_idx, const float* __restrict__ fg_xyz,
    const float* __restrict__ fg_ctr, const float* __restrict__ offs,
    float* __restrict__ out_feat, float* __restrict__ out_agg,
    float* __restrict__ out_cxyz, float* __restrict__ out_coff,
    float* __restrict__ out_corg) {
  int b = blockIdx.z;
  if (blockIdx.y < 32) {
    int o = blockIdx.y * 4 + (threadIdx.x >> 6);
    int s = blockIdx.x * 64 + (threadIdx.x & 63);
    float val;
    if (s < NS) {
      int i = ctr_idx[b * NS + s];
      val = vh[((size_t)b * NH + o) * NM + i];
    } else {
      int i = ori_idx[b * NS + (s - NS)];
      int g = fg_idx[b * NM + i];
      val = features[((size_t)b * NC + o) * NP + g];
    }
    out_feat[((size_t)b * NH + o) * (2 * NS) + s] = val;
  } else if (blockIdx.x < 8) {
    int s = blockIdx.x * 256 + threadIdx.x;  // 0..2047
    if (s < NS) {
      int i = ctr_idx[b * NS + s];
      size_t src = ((size_t)b * NM + i) * 3;
      size_t d_agg = ((size_t)b * 2 * NS + s) * 3;
      size_t d_s = ((size_t)b * NS + s) * 3;
#pragma unroll
      for (int r = 0; r < 3; ++r) {
        float c = fg_ctr[src + r];
        out_agg[d_agg + r] = c;
        out_cxyz[d_s + r] = c;
        out_coff[d_s + r] = offs[src + r];
        out_corg[d_s + r] = fg_xyz[src + r];
      }
    } else {
      int i = ori_idx[b * NS + (s - NS)];
      size_t src = ((size_t)b * NM + i) * 3;
      size_t d_agg = ((size_t)b * 2 * NS + s) * 3;
#pragma unroll
      for (int r = 0; r < 3; ++r) out_agg[d_agg + r] = fg_xyz[src + r];
    }
  }
}

extern "C" void kernel_launch(void* const* d_in, const int* in_sizes, int n_in,
                              void* d_out, int out_size, void* d_ws, size_t ws_size,
                              hipStream_t stream) {
  const float* xyz = (const float*)d_in[0];
  const float* features = (const float*)d_in[1];
  const float* seg_w1 = (const float*)d_in[2];
  const float* seg_scale1 = (const float*)d_in[3];
  const float* seg_bias1 = (const float*)d_in[4];
  const float* seg_w2 = (const float*)d_in[5];
  const float* seg_b2 = (const float*)d_in[6];
  const float* vote_w1 = (const float*)d_in[7];
  const float* vote_scale1 = (const float*)d_in[8];
  const float* vote_bias1 = (const float*)d_in[9];
  const float* reg_w = (const float*)d_in[10];
  const float* reg_b = (const float*)d_in[11];
  float* out = (float*)d_out;

  char* ws = (char*)d_ws;
  unsigned long long* keys = (unsigned long long*)(ws + 0);  // 1,048,576 B
  int* fg_idx = (int*)(ws + 1048576);                        // 131,072 B
  float* fg_xyz = (float*)(ws + 1179648);                    // 393,216 B
  float* fg_ctr = (float*)(ws + 1572864);                    // 393,216 B
  float* offs = (float*)(ws + 1966080);                      // 393,216 B
  int* ori_idx = (int*)(ws + 2359296);                       // 32,768 B
  int* ctr_idx = (int*)(ws + 2392064);                       // 32,768 B
  float* vh = (float*)(ws + 2424832);                        // 16,777,216 B

  // outputs (reference return order), seg is [B,128,N]:
  float* out_agg_xyz = out;                  // [8,2048,3]      @ 0
  float* out_agg_feat = out + 49152;         // [8,128,2048]    @ 49152
  float* out_ctr_xyz = out + 2146304;        // [8,1024,3]      @ 2146304
  float* out_ctr_off = out + 2170880;        // [8,1024,3]      @ 2170880
  float* out_ctr_org = out + 2195456;        // [8,1024,3]      @ 2195456
  float* out_seg = out + 2220032;            // [8,128,16384]   @ 2220032

  seg_kernel<<<dim3(NP / 128, NB), 256, 0, stream>>>(
      seg_w1, features, seg_scale1, seg_bias1, seg_w2, seg_b2, out_seg, keys);
  sort8k_kernel<<<2 * NB, 1024, 0, stream>>>(keys);
  merge_topk_kernel<<<NB, 1024, 0, stream>>>(keys, fg_idx, fg_xyz, xyz);
  vote_kernel<<<dim3(NM / 64, NB), 256, 0, stream>>>(
      features, fg_idx, vote_w1, vote_scale1, vote_bias1, reg_w, reg_b, fg_xyz,
      vh, offs, fg_ctr);
  fps_kernel<<<16, 256, 0, stream>>>(fg_xyz, fg_ctr, ori_idx, ctr_idx);
  out_kernel<<<dim3(32, 33, NB), 256, 0, stream>>>(
      vh, features, fg_idx, ori_idx, ctr_idx, fg_xyz, fg_ctr, offs,
      out_agg_feat, out_agg_xyz, out_ctr_xyz, out_ctr_off, out_ctr_org);
}